// Round 2
// baseline (390.391 us; speedup 1.0000x reference)
//
#include <hip/hip_runtime.h>
#include <math.h>

#define NT 2
#define BSZ 4
#define NAT 512
#define NATOMS 2048
#define NNEI 200
#define EMB 100
#define FITH 240
#define DDIM 1600
#define TBK 2048          // table knots per net
#define TBL_OFF 64        // float offset of tables in ws
#define H1_OFF (TBL_OFF + 4 * TBK * EMB)            // h1 scratch for table build
#define WS_NEED ((size_t)(H1_OFF + 4 * TBK * 50) * 4)

__device__ __forceinline__ float ftanh(float x) {
    float ax = fabsf(x);
    float e = __expf(2.0f * ax);
    float t = 1.0f - __fdividef(2.0f, e + 1.0f);
    return (x < 0.0f) ? -t : t;
}

// sortable-uint encoding of float for atomicMin/Max
__device__ __forceinline__ unsigned fenc(float f) {
    unsigned b = __float_as_uint(f);
    return (b & 0x80000000u) ? ~b : (b | 0x80000000u);
}
__device__ __forceinline__ float fdec(unsigned u) {
    unsigned b = (u & 0x80000000u) ? (u & 0x7fffffffu) : ~u;
    return __uint_as_float(b);
}

__device__ __forceinline__ float calc_S(float R) {
    float Rsafe = (R > 1e-5f) ? R : 1.0f;
    float u = (R - 0.5f) * (1.0f / 5.5f);
    float uu = u * u;
    float mid = (u * uu * (-6.0f * uu + 15.0f * u - 10.0f) + 1.0f) / Rsafe;
    float S = 0.0f;
    if (R > 0.0f && R < 0.5f)      S = 1.0f / Rsafe;
    else if (R > 0.5f && R < 6.0f) S = mid;
    return S;
}

// ---------- K0: init range slots ----------
__global__ void init_kernel(unsigned* __restrict__ wsu) {
    int tid = threadIdx.x;
    if (tid < 4) { wsu[2 * tid] = 0xFFFFFFFFu; wsu[2 * tid + 1] = 0u; }
}

// ---------- K1: scan s range per net (t,j) ----------
__global__ void scan_kernel(const int* __restrict__ itype,
                            const float* __restrict__ imagedr,
                            const float* __restrict__ davg,
                            const float* __restrict__ dstd,
                            unsigned* __restrict__ wsu) {
    const int atom = blockIdx.x;
    const int n = atom & (NAT - 1);
    const int tid = threadIdx.x;
    const int t = itype[n];
    __shared__ float mn[2][128], mx[2][128];
    for (int i = tid; i < 256; i += 256) {
        mn[i >> 7][i & 127] = 1e30f;
        mx[i >> 7][i & 127] = -1e30f;
    }
    __syncthreads();
    if (tid < NNEI) {
        float R = imagedr[((size_t)atom * NNEI + tid) * 4];
        float S = calc_S(R);
        float av = davg[t * 800 + tid * 4];
        float sd = dstd[t * 800 + tid * 4];
        float s = (S - av) / sd;
        int j = (tid >= 100);
        int q = tid - j * 100;
        mn[j][q] = s; mx[j][q] = s;
    }
    __syncthreads();
    int g = tid >> 7, q = tid & 127;
    for (int str = 64; str >= 1; str >>= 1) {
        if (q < str) {
            mn[g][q] = fminf(mn[g][q], mn[g][q + str]);
            mx[g][q] = fmaxf(mx[g][q], mx[g][q + str]);
        }
        __syncthreads();
    }
    if (tid == 0) {
        atomicMin(&wsu[2 * (t * 2 + 0)],     fenc(mn[0][0]));
        atomicMax(&wsu[2 * (t * 2 + 0) + 1], fenc(mx[0][0]));
        atomicMin(&wsu[2 * (t * 2 + 1)],     fenc(mn[1][0]));
        atomicMax(&wsu[2 * (t * 2 + 1) + 1], fenc(mx[1][0]));
    }
}

// ---------- K2a: table build stage 1 (h1 per knot) ----------
__global__ void table_h1_kernel(const float* __restrict__ eW0, const float* __restrict__ eb0,
                                const float* __restrict__ eW1, const float* __restrict__ eb1,
                                float* __restrict__ ws) {
    const unsigned* wsu = (const unsigned*)ws;
    int gid = blockIdx.x * 256 + threadIdx.x;   // 4*TBK
    int k = gid & (TBK - 1);
    int nid = gid >> 11;
    float smin = fdec(wsu[2 * nid]);
    float smax = fdec(wsu[2 * nid + 1]);
    float span = smax - smin;
    if (!(span >= 0.0f)) { smin = 0.0f; span = 0.0f; }
    float s = smin + span * ((float)k * (1.0f / (TBK - 1)));
    const float* W0 = eW0 + nid * 25;
    const float* B0 = eb0 + nid * 25;
    const float* W1 = eW1 + nid * 25 * 50;
    const float* B1 = eb1 + nid * 50;
    float h0[25];
#pragma unroll
    for (int a = 0; a < 25; ++a) h0[a] = ftanh(fmaf(s, W0[a], B0[a]));
    float* h1o = ws + H1_OFF + (size_t)(nid * TBK + k) * 50;
#pragma unroll
    for (int cc = 0; cc < 50; ++cc) {
        float acc = B1[cc];
#pragma unroll
        for (int a = 0; a < 25; ++a) acc = fmaf(h0[a], W1[a * 50 + cc], acc);
        h1o[cc] = ftanh(acc) + h0[(cc < 25) ? cc : cc - 25];
    }
}

// ---------- K2b: table build stage 2 (G per knot,channel) ----------
__global__ void table_g_kernel(const float* __restrict__ eW2, const float* __restrict__ eb2,
                               float* __restrict__ ws) {
    int gid = blockIdx.x * 256 + threadIdx.x;   // 4*TBK*100
    int c = gid % 100;
    int r = gid / 100;
    int k = r & (TBK - 1);
    int nid = r >> 11;
    const float* h1 = ws + H1_OFF + (size_t)(nid * TBK + k) * 50;
    const float* W2 = eW2 + nid * 50 * 100;
    float acc = eb2[nid * 100 + c];
#pragma unroll
    for (int a = 0; a < 50; ++a) acc = fmaf(h1[a], W2[a * 100 + c], acc);
    float g = ftanh(acc) + h1[(c < 50) ? c : c - 50];
    ws[TBL_OFF + (size_t)(nid * TBK + k) * EMB + c] = g;
}

// ---------- K3: main fused kernel — 1 block = 4 atoms (same n, 4 batches) ----------
__global__ void __launch_bounds__(256) main_kernel(
    const int*   __restrict__ itype,
    const float* __restrict__ imagedr,
    const float* __restrict__ davg,
    const float* __restrict__ dstd,
    const float* __restrict__ fW0, const float* __restrict__ fb0,
    const float* __restrict__ fW1, const float* __restrict__ fb1,
    const float* __restrict__ fW2, const float* __restrict__ fb2,
    const float* __restrict__ fW3, const float* __restrict__ fb3,
    const float* __restrict__ eshift,
    const float* __restrict__ ws,
    float*       __restrict__ out)
{
    __shared__ __align__(16) float4 rn4[4][NNEI];     // 12.8 KB
    __shared__ int   sidx[4][NNEI];                   // 3.2 KB
    __shared__ float sfrc[4][NNEI];                   // 3.2 KB
    __shared__ __align__(16) float xyz[4][4 * EMB];   // 6.4 KB
    __shared__ __align__(16) float D4[4][DDIM];       // 25.6 KB
    __shared__ __align__(16) float hA[4][FITH];       // 3.84 KB
    __shared__ __align__(16) float hB[4][FITH];       // 3.84 KB
    __shared__ float red[4][4];

    const int n   = blockIdx.x;       // 0..511
    const int tid = threadIdx.x;
    const int t   = itype[n];

    const unsigned* wsu = (const unsigned*)ws;
    float sm0 = fdec(wsu[2 * (t * 2 + 0)]);
    float sp0 = fdec(wsu[2 * (t * 2 + 0) + 1]) - sm0;
    float sm1 = fdec(wsu[2 * (t * 2 + 1)]);
    float sp1 = fdec(wsu[2 * (t * 2 + 1) + 1]) - sm1;
    float sc0 = (sp0 > 0.0f) ? (float)(TBK - 1) / sp0 : 0.0f;
    float sc1 = (sp1 > 0.0f) ? (float)(TBK - 1) / sp1 : 0.0f;

    // ---- Phase A: Rn + table coords ----
    for (int slot = tid; slot < 4 * NNEI; slot += 256) {
        int aa = slot / NNEI;
        int m  = slot - aa * NNEI;
        float4 dr = ((const float4*)imagedr)[(size_t)(aa * NAT + n) * NNEI + m];
        float R = dr.x;
        float S = calc_S(R);
        float Rsafe = (R > 1e-5f) ? R : 1.0f;
        float sr = (fabsf(R) > 1e-5f) ? (S / Rsafe) : 0.0f;
        float4 av = ((const float4*)davg)[t * NNEI + m];
        float4 sd = ((const float4*)dstd)[t * NNEI + m];
        float4 rv;
        rv.x = (S         - av.x) / sd.x;
        rv.y = (sr * dr.y - av.y) / sd.y;
        rv.z = (sr * dr.z - av.z) / sd.z;
        rv.w = (sr * dr.w - av.w) / sd.w;
        rn4[aa][m] = rv;
        float smin = (m >= 100) ? sm1 : sm0;
        float scal = (m >= 100) ? sc1 : sc0;
        float x = fmaxf((rv.x - smin) * scal, 0.0f);
        int i = (int)x;
        if (i > TBK - 2) i = TBK - 2;
        sidx[aa][m] = i;
        sfrc[aa][m] = x - (float)i;
    }
    __syncthreads();

    // ---- Phase B: table interp + xyz accumulate (1 wave per atom) ----
    {
        const int aa = tid >> 6;
        const int lane = tid & 63;
        float xA0 = 0, xA1 = 0, xA2 = 0, xA3 = 0;
        float xB0 = 0, xB1 = 0, xB2 = 0, xB3 = 0;
        const float* T0 = ws + TBL_OFF + (size_t)(t * 2 + 0) * TBK * EMB;
        const float* T1 = ws + TBL_OFF + (size_t)(t * 2 + 1) * TBK * EMB;
        const bool hi = (lane < 36);
        for (int half = 0; half < 2; ++half) {
            const float* T = half ? T1 : T0;
            int mbase = half * 100;
            for (int mi = 0; mi < 100; ++mi) {
                int m = mbase + mi;
                float4 rv = rn4[aa][m];
                int i = sidx[aa][m];
                float f = sfrc[aa][m];
                const float* Tr = T + (size_t)i * EMB;
                float g0 = Tr[lane];
                float g = fmaf(f, Tr[EMB + lane] - g0, g0);
                xA0 = fmaf(rv.x, g, xA0); xA1 = fmaf(rv.y, g, xA1);
                xA2 = fmaf(rv.z, g, xA2); xA3 = fmaf(rv.w, g, xA3);
                if (hi) {
                    float h0v = Tr[64 + lane];
                    float g2 = fmaf(f, Tr[EMB + 64 + lane] - h0v, h0v);
                    xB0 = fmaf(rv.x, g2, xB0); xB1 = fmaf(rv.y, g2, xB1);
                    xB2 = fmaf(rv.z, g2, xB2); xB3 = fmaf(rv.w, g2, xB3);
                }
            }
        }
        const float inv = 1.0f / 200.0f;
        xyz[aa][0 * EMB + lane] = xA0 * inv;
        xyz[aa][1 * EMB + lane] = xA1 * inv;
        xyz[aa][2 * EMB + lane] = xA2 * inv;
        xyz[aa][3 * EMB + lane] = xA3 * inv;
        if (hi) {
            xyz[aa][0 * EMB + 64 + lane] = xB0 * inv;
            xyz[aa][1 * EMB + 64 + lane] = xB1 * inv;
            xyz[aa][2 * EMB + 64 + lane] = xB2 * inv;
            xyz[aa][3 * EMB + 64 + lane] = xB3 * inv;
        }
    }
    __syncthreads();

    // ---- Phase C: D[aa][c*16+d] ----
    for (int i2 = tid; i2 < 4 * DDIM; i2 += 256) {
        int aa = i2 / DDIM;
        int r  = i2 - aa * DDIM;
        int cc = r >> 4, d = r & 15;
        const float* xz = xyz[aa];
        float acc = xz[cc] * xz[d]
                  + xz[EMB + cc]     * xz[EMB + d]
                  + xz[2 * EMB + cc] * xz[2 * EMB + d]
                  + xz[3 * EMB + cc] * xz[3 * EMB + d];
        D4[aa][r] = acc;
    }
    __syncthreads();

    const int o  = tid;
    const int oc = (o < FITH) ? o : (FITH - 1);   // clamp keeps loads in-bounds

    // ---- fit layer 0: 1600 -> 240, 4 atoms ----
    {
        const float* W = fW0 + (size_t)t * DDIM * FITH;
        float b = fb0[t * FITH + oc];
        float a0 = b, a1 = b, a2 = b, a3 = b;
#pragma unroll 2
        for (int f = 0; f < DDIM; f += 4) {
            float w0 = W[(f + 0) * FITH + oc];
            float w1 = W[(f + 1) * FITH + oc];
            float w2 = W[(f + 2) * FITH + oc];
            float w3 = W[(f + 3) * FITH + oc];
            float4 d0 = *(const float4*)&D4[0][f];
            float4 d1 = *(const float4*)&D4[1][f];
            float4 d2 = *(const float4*)&D4[2][f];
            float4 d3 = *(const float4*)&D4[3][f];
            a0 = fmaf(d0.x, w0, a0); a0 = fmaf(d0.y, w1, a0); a0 = fmaf(d0.z, w2, a0); a0 = fmaf(d0.w, w3, a0);
            a1 = fmaf(d1.x, w0, a1); a1 = fmaf(d1.y, w1, a1); a1 = fmaf(d1.z, w2, a1); a1 = fmaf(d1.w, w3, a1);
            a2 = fmaf(d2.x, w0, a2); a2 = fmaf(d2.y, w1, a2); a2 = fmaf(d2.z, w2, a2); a2 = fmaf(d2.w, w3, a2);
            a3 = fmaf(d3.x, w0, a3); a3 = fmaf(d3.y, w1, a3); a3 = fmaf(d3.z, w2, a3); a3 = fmaf(d3.w, w3, a3);
        }
        if (o < FITH) {
            hA[0][o] = ftanh(a0); hA[1][o] = ftanh(a1);
            hA[2][o] = ftanh(a2); hA[3][o] = ftanh(a3);
        }
    }
    __syncthreads();

    // ---- fit layer 1 ----
    {
        const float* W = fW1 + (size_t)t * FITH * FITH;
        float b = fb1[t * FITH + oc];
        float a0 = b, a1 = b, a2 = b, a3 = b;
#pragma unroll 2
        for (int f = 0; f < FITH; f += 4) {
            float w0 = W[(f + 0) * FITH + oc];
            float w1 = W[(f + 1) * FITH + oc];
            float w2 = W[(f + 2) * FITH + oc];
            float w3 = W[(f + 3) * FITH + oc];
            float4 d0 = *(const float4*)&hA[0][f];
            float4 d1 = *(const float4*)&hA[1][f];
            float4 d2 = *(const float4*)&hA[2][f];
            float4 d3 = *(const float4*)&hA[3][f];
            a0 = fmaf(d0.x, w0, a0); a0 = fmaf(d0.y, w1, a0); a0 = fmaf(d0.z, w2, a0); a0 = fmaf(d0.w, w3, a0);
            a1 = fmaf(d1.x, w0, a1); a1 = fmaf(d1.y, w1, a1); a1 = fmaf(d1.z, w2, a1); a1 = fmaf(d1.w, w3, a1);
            a2 = fmaf(d2.x, w0, a2); a2 = fmaf(d2.y, w1, a2); a2 = fmaf(d2.z, w2, a2); a2 = fmaf(d2.w, w3, a2);
            a3 = fmaf(d3.x, w0, a3); a3 = fmaf(d3.y, w1, a3); a3 = fmaf(d3.z, w2, a3); a3 = fmaf(d3.w, w3, a3);
        }
        if (o < FITH) {
            hB[0][o] = hA[0][o] + ftanh(a0); hB[1][o] = hA[1][o] + ftanh(a1);
            hB[2][o] = hA[2][o] + ftanh(a2); hB[3][o] = hA[3][o] + ftanh(a3);
        }
    }
    __syncthreads();

    // ---- fit layer 2 (result into hA) ----
    {
        const float* W = fW2 + (size_t)t * FITH * FITH;
        float b = fb2[t * FITH + oc];
        float a0 = b, a1 = b, a2 = b, a3 = b;
#pragma unroll 2
        for (int f = 0; f < FITH; f += 4) {
            float w0 = W[(f + 0) * FITH + oc];
            float w1 = W[(f + 1) * FITH + oc];
            float w2 = W[(f + 2) * FITH + oc];
            float w3 = W[(f + 3) * FITH + oc];
            float4 d0 = *(const float4*)&hB[0][f];
            float4 d1 = *(const float4*)&hB[1][f];
            float4 d2 = *(const float4*)&hB[2][f];
            float4 d3 = *(const float4*)&hB[3][f];
            a0 = fmaf(d0.x, w0, a0); a0 = fmaf(d0.y, w1, a0); a0 = fmaf(d0.z, w2, a0); a0 = fmaf(d0.w, w3, a0);
            a1 = fmaf(d1.x, w0, a1); a1 = fmaf(d1.y, w1, a1); a1 = fmaf(d1.z, w2, a1); a1 = fmaf(d1.w, w3, a1);
            a2 = fmaf(d2.x, w0, a2); a2 = fmaf(d2.y, w1, a2); a2 = fmaf(d2.z, w2, a2); a2 = fmaf(d2.w, w3, a2);
            a3 = fmaf(d3.x, w0, a3); a3 = fmaf(d3.y, w1, a3); a3 = fmaf(d3.z, w2, a3); a3 = fmaf(d3.w, w3, a3);
        }
        __syncthreads();  // hB still being read above; ensure all reads done before overwrite of hA? hA dead; safe.
        if (o < FITH) {
            hA[0][o] = hB[0][o] + ftanh(a0); hA[1][o] = hB[1][o] + ftanh(a1);
            hA[2][o] = hB[2][o] + ftanh(a2); hA[3][o] = hB[3][o] + ftanh(a3);
        }
    }
    __syncthreads();

    // ---- final dot ----
    {
        float w3 = (o < FITH) ? fW3[t * FITH + o] : 0.0f;
        float p0 = (o < FITH) ? hA[0][o] * w3 : 0.0f;
        float p1 = (o < FITH) ? hA[1][o] * w3 : 0.0f;
        float p2 = (o < FITH) ? hA[2][o] * w3 : 0.0f;
        float p3 = (o < FITH) ? hA[3][o] * w3 : 0.0f;
#pragma unroll
        for (int off = 32; off > 0; off >>= 1) {
            p0 += __shfl_down(p0, off, 64);
            p1 += __shfl_down(p1, off, 64);
            p2 += __shfl_down(p2, off, 64);
            p3 += __shfl_down(p3, off, 64);
        }
        int w = tid >> 6;
        if ((tid & 63) == 0) {
            red[0][w] = p0; red[1][w] = p1; red[2][w] = p2; red[3][w] = p3;
        }
    }
    __syncthreads();
    if (tid < 4) {
        float e = red[tid][0] + red[tid][1] + red[tid][2] + red[tid][3] + fb3[t] + eshift[t];
        out[4 + tid * NAT + n] = e;
    }
}

__global__ void etot_kernel(float* __restrict__ out) {
    const int b = blockIdx.x;
    float s = 0.0f;
    for (int n = threadIdx.x; n < NAT; n += 256) s += out[4 + b * NAT + n];
#pragma unroll
    for (int off = 32; off > 0; off >>= 1) s += __shfl_down(s, off, 64);
    __shared__ float rr[4];
    if ((threadIdx.x & 63) == 0) rr[threadIdx.x >> 6] = s;
    __syncthreads();
    if (threadIdx.x == 0) out[b] = rr[0] + rr[1] + rr[2] + rr[3];
}

// ================= fallback: round-1 monolithic kernel =================
__global__ void dp_atom_kernel(
    const int* __restrict__ itype, const float* __restrict__ imagedr,
    const float* __restrict__ davg, const float* __restrict__ dstd,
    const float* __restrict__ eW0, const float* __restrict__ eb0,
    const float* __restrict__ eW1, const float* __restrict__ eb1,
    const float* __restrict__ eW2, const float* __restrict__ eb2,
    const float* __restrict__ fW0, const float* __restrict__ fb0,
    const float* __restrict__ fW1, const float* __restrict__ fb1,
    const float* __restrict__ fW2, const float* __restrict__ fb2,
    const float* __restrict__ fW3, const float* __restrict__ fb3,
    const float* __restrict__ eshift, float* __restrict__ out)
{
    __shared__ __align__(16) float4 rn4[NNEI];
    __shared__ __align__(16) float  xyz[4 * EMB];
    __shared__ __align__(16) float  h0s[100 * 25];
    __shared__ __align__(16) float  smem[100 * 52];
    const int atom = blockIdx.x;
    const int n = atom & (NAT - 1);
    const int tid = threadIdx.x;
    const int t = itype[n];
    for (int m = tid; m < NNEI; m += 256) {
        float4 dr = ((const float4*)imagedr)[(size_t)atom * NNEI + m];
        float R = dr.x;
        float S = calc_S(R);
        float Rsafe = (R > 1e-5f) ? R : 1.0f;
        float sr = (fabsf(R) > 1e-5f) ? (S / Rsafe) : 0.0f;
        float4 av = ((const float4*)davg)[t * NNEI + m];
        float4 sd = ((const float4*)dstd)[t * NNEI + m];
        float4 rv;
        rv.x = (S - av.x) / sd.x; rv.y = (sr * dr.y - av.y) / sd.y;
        rv.z = (sr * dr.z - av.z) / sd.z; rv.w = (sr * dr.w - av.w) / sd.w;
        rn4[m] = rv;
    }
    const int c = tid & 127; const int mh = tid >> 7;
    float xp0 = 0, xp1 = 0, xp2 = 0, xp3 = 0;
    for (int j = 0; j < NT; ++j) {
        const int wb = t * NT + j;
        const float* W0 = eW0 + wb * 25; const float* B0 = eb0 + wb * 25;
        const float* W1 = eW1 + wb * 1250; const float* B1 = eb1 + wb * 50;
        const float* W2 = eW2 + wb * 5000; const float* B2 = eb2 + wb * 100;
        __syncthreads();
        for (int idx = tid; idx < 2500; idx += 256) {
            int m = idx / 25, a = idx - m * 25;
            h0s[idx] = ftanh(fmaf(rn4[j * 100 + m].x, W0[a], B0[a]));
        }
        __syncthreads();
        for (int idx = tid; idx < 5000; idx += 256) {
            int m = idx / 50, cc = idx - m * 50;
            const float* h0m = h0s + m * 25;
            float acc = B1[cc];
#pragma unroll
            for (int a = 0; a < 25; ++a) acc = fmaf(h0m[a], W1[a * 50 + cc], acc);
            smem[m * 52 + cc] = ftanh(acc) + h0m[(cc < 25) ? cc : cc - 25];
        }
        for (int idx = tid; idx < 200; idx += 256)
            smem[(idx >> 1) * 52 + 50 + (idx & 1)] = 0.0f;
        __syncthreads();
        if (c < EMB) {
            float w2c[52];
#pragma unroll
            for (int a = 0; a < 50; ++a) w2c[a] = W2[a * EMB + c];
            w2c[50] = 0; w2c[51] = 0;
            const float bc = B2[c];
            const int sk = (c < 50) ? c : c - 50;
            for (int i = 0; i < 50; ++i) {
                int m = mh * 50 + i;
                const float* h1m = smem + m * 52;
                float acc = bc;
#pragma unroll
                for (int q = 0; q < 13; ++q) {
                    float4 hv = ((const float4*)h1m)[q];
                    acc = fmaf(hv.x, w2c[4 * q], acc); acc = fmaf(hv.y, w2c[4 * q + 1], acc);
                    acc = fmaf(hv.z, w2c[4 * q + 2], acc); acc = fmaf(hv.w, w2c[4 * q + 3], acc);
                }
                float g = ftanh(acc) + h1m[sk];
                float4 rm = rn4[j * 100 + m];
                xp0 = fmaf(rm.x, g, xp0); xp1 = fmaf(rm.y, g, xp1);
                xp2 = fmaf(rm.z, g, xp2); xp3 = fmaf(rm.w, g, xp3);
            }
        }
    }
    __syncthreads();
    const float inv = 1.0f / 200.0f;
    if (mh == 0 && c < EMB) {
        xyz[c] = xp0 * inv; xyz[EMB + c] = xp1 * inv;
        xyz[2 * EMB + c] = xp2 * inv; xyz[3 * EMB + c] = xp3 * inv;
    }
    __syncthreads();
    if (mh == 1 && c < EMB) {
        xyz[c] += xp0 * inv; xyz[EMB + c] += xp1 * inv;
        xyz[2 * EMB + c] += xp2 * inv; xyz[3 * EMB + c] += xp3 * inv;
    }
    __syncthreads();
    float* Dld = smem;
    for (int idx = tid; idx < DDIM; idx += 256) {
        int cc = idx >> 4, d = idx & 15;
        Dld[idx] = xyz[cc] * xyz[d] + xyz[EMB + cc] * xyz[EMB + d]
                 + xyz[2 * EMB + cc] * xyz[2 * EMB + d] + xyz[3 * EMB + cc] * xyz[3 * EMB + d];
    }
    __syncthreads();
    float* hA = smem + DDIM; float* hB = hA + FITH; float* h2 = hB + FITH; float* red = h2 + FITH;
    if (tid < FITH) {
        const float* W = fW0 + (size_t)t * DDIM * FITH;
        float acc = fb0[t * FITH + tid];
        for (int f = 0; f < DDIM; f += 4) {
            float4 dv = *(const float4*)(Dld + f);
            acc = fmaf(dv.x, W[f * FITH + tid], acc); acc = fmaf(dv.y, W[(f + 1) * FITH + tid], acc);
            acc = fmaf(dv.z, W[(f + 2) * FITH + tid], acc); acc = fmaf(dv.w, W[(f + 3) * FITH + tid], acc);
        }
        hA[tid] = ftanh(acc);
    }
    __syncthreads();
    if (tid < FITH) {
        const float* W = fW1 + t * FITH * FITH;
        float acc = fb1[t * FITH + tid];
        for (int f = 0; f < FITH; f += 4) {
            float4 hv = *(const float4*)(hA + f);
            acc = fmaf(hv.x, W[f * FITH + tid], acc); acc = fmaf(hv.y, W[(f + 1) * FITH + tid], acc);
            acc = fmaf(hv.z, W[(f + 2) * FITH + tid], acc); acc = fmaf(hv.w, W[(f + 3) * FITH + tid], acc);
        }
        hB[tid] = hA[tid] + ftanh(acc);
    }
    __syncthreads();
    if (tid < FITH) {
        const float* W = fW2 + t * FITH * FITH;
        float acc = fb2[t * FITH + tid];
        for (int f = 0; f < FITH; f += 4) {
            float4 hv = *(const float4*)(hB + f);
            acc = fmaf(hv.x, W[f * FITH + tid], acc); acc = fmaf(hv.y, W[(f + 1) * FITH + tid], acc);
            acc = fmaf(hv.z, W[(f + 2) * FITH + tid], acc); acc = fmaf(hv.w, W[(f + 3) * FITH + tid], acc);
        }
        h2[tid] = hB[tid] + ftanh(acc);
    }
    __syncthreads();
    float p = (tid < FITH) ? h2[tid] * fW3[t * FITH + tid] : 0.0f;
#pragma unroll
    for (int off = 32; off > 0; off >>= 1) p += __shfl_down(p, off, 64);
    if ((tid & 63) == 0) red[tid >> 6] = p;
    __syncthreads();
    if (tid == 0) out[4 + atom] = red[0] + red[1] + red[2] + red[3] + fb3[t] + eshift[t];
}

extern "C" void kernel_launch(void* const* d_in, const int* in_sizes, int n_in,
                              void* d_out, int out_size, void* d_ws, size_t ws_size,
                              hipStream_t stream) {
    const int*   itype   = (const int*)  d_in[1];
    const float* imagedr = (const float*)d_in[3];
    const float* davg    = (const float*)d_in[5];
    const float* dstd    = (const float*)d_in[6];
    const float* eW0     = (const float*)d_in[7];
    const float* eb0     = (const float*)d_in[8];
    const float* eW1     = (const float*)d_in[9];
    const float* eb1     = (const float*)d_in[10];
    const float* eW2     = (const float*)d_in[11];
    const float* eb2     = (const float*)d_in[12];
    const float* fW0     = (const float*)d_in[13];
    const float* fb0     = (const float*)d_in[14];
    const float* fW1     = (const float*)d_in[15];
    const float* fb1     = (const float*)d_in[16];
    const float* fW2     = (const float*)d_in[17];
    const float* fb2     = (const float*)d_in[18];
    const float* fW3     = (const float*)d_in[19];
    const float* fb3     = (const float*)d_in[20];
    const float* eshift  = (const float*)d_in[21];
    float* out = (float*)d_out;

    if (ws_size >= WS_NEED) {
        float* ws = (float*)d_ws;
        unsigned* wsu = (unsigned*)d_ws;
        init_kernel<<<1, 64, 0, stream>>>(wsu);
        scan_kernel<<<NATOMS, 256, 0, stream>>>(itype, imagedr, davg, dstd, wsu);
        table_h1_kernel<<<4 * TBK / 256, 256, 0, stream>>>(eW0, eb0, eW1, eb1, ws);
        table_g_kernel<<<4 * TBK * 100 / 256, 256, 0, stream>>>(eW2, eb2, ws);
        main_kernel<<<NAT, 256, 0, stream>>>(itype, imagedr, davg, dstd,
            fW0, fb0, fW1, fb1, fW2, fb2, fW3, fb3, eshift, ws, out);
    } else {
        dp_atom_kernel<<<NATOMS, 256, 0, stream>>>(itype, imagedr, davg, dstd,
            eW0, eb0, eW1, eb1, eW2, eb2,
            fW0, fb0, fW1, fb1, fW2, fb2, fW3, fb3, eshift, out);
    }
    etot_kernel<<<BSZ, 256, 0, stream>>>(out);
}

// Round 3
// 334.048 us; speedup vs baseline: 1.1687x; 1.1687x over previous
//
#include <hip/hip_runtime.h>
#include <math.h>

#define NT 2
#define BSZ 4
#define NAT 512
#define NATOMS 2048
#define NNEI 200
#define EMB 100
#define FITH 240
#define DDIM 1600
#define TBK 2048

// ---- ws layout (float offsets) ----
#define RANGE_OFF 0                         // 8 floats: [net*2]=min, [net*2+1]=max, net=t*2+j
#define PART_OFF  16                        // 128 blocks x 8
#define TBL_OFF   1088                      // 4*2048*100 = 819200
#define H1_OFF    (TBL_OFF + 4 * TBK * EMB)            // 820288, 4*2048*50 = 409600
#define WT0_OFF   (H1_OFF + 4 * TBK * 50)              // 1229888, W0T: 2*240*1600 = 768000
#define WT1_OFF   (WT0_OFF + 768000)                   // W1T: 2*240*240 = 115200
#define WT2_OFF   (WT1_OFF + 115200)                   // W2T: 115200
#define XYZ_OFF   (WT2_OFF + 115200)                   // 2228288, 2048*400 = 819200
#define WS_FULL   ((size_t)(XYZ_OFF + NATOMS * 400) * 4)     // ~12.2 MB
#define WS_LITE   ((size_t)WT0_OFF * 4)                      // ~4.92 MB

__device__ __forceinline__ float ftanh(float x) {
    float ax = fabsf(x);
    float e = __expf(2.0f * ax);
    float t = 1.0f - __fdividef(2.0f, e + 1.0f);
    return (x < 0.0f) ? -t : t;
}

__device__ __forceinline__ float calc_S(float R) {
    float Rsafe = (R > 1e-5f) ? R : 1.0f;
    float u = (R - 0.5f) * (1.0f / 5.5f);
    float uu = u * u;
    float mid = (u * uu * (-6.0f * uu + 15.0f * u - 10.0f) + 1.0f) / Rsafe;
    float S = 0.0f;
    if (R > 0.0f && R < 0.5f)      S = 1.0f / Rsafe;
    else if (R > 0.5f && R < 6.0f) S = mid;
    return S;
}

// ---------- K1: atomic-free range scan: 128 blocks write partial min/max ----------
__global__ void scan2_kernel(const int* __restrict__ itype,
                             const float* __restrict__ imagedr,
                             const float* __restrict__ davg,
                             const float* __restrict__ dstd,
                             float* __restrict__ ws) {
    const int tid = threadIdx.x;
    float mn0 = 1e30f, mx0 = -1e30f, mn1 = 1e30f, mx1 = -1e30f;
    float mn2 = 1e30f, mx2 = -1e30f, mn3 = 1e30f, mx3 = -1e30f;
    for (int i = blockIdx.x * 256 + tid; i < NATOMS * NNEI; i += 128 * 256) {
        int atom = i / NNEI;
        int m = i - atom * NNEI;
        int n = atom & (NAT - 1);
        int t = itype[n];
        float R = imagedr[(size_t)i * 4];
        float S = calc_S(R);
        float av = davg[(t * NNEI + m) * 4];
        float sd = dstd[(t * NNEI + m) * 4];
        float s = (S - av) / sd;
        int net = t * 2 + (m >= 100 ? 1 : 0);
        if (net == 0)      { mn0 = fminf(mn0, s); mx0 = fmaxf(mx0, s); }
        else if (net == 1) { mn1 = fminf(mn1, s); mx1 = fmaxf(mx1, s); }
        else if (net == 2) { mn2 = fminf(mn2, s); mx2 = fmaxf(mx2, s); }
        else               { mn3 = fminf(mn3, s); mx3 = fmaxf(mx3, s); }
    }
#pragma unroll
    for (int off = 32; off > 0; off >>= 1) {
        mn0 = fminf(mn0, __shfl_down(mn0, off, 64)); mx0 = fmaxf(mx0, __shfl_down(mx0, off, 64));
        mn1 = fminf(mn1, __shfl_down(mn1, off, 64)); mx1 = fmaxf(mx1, __shfl_down(mx1, off, 64));
        mn2 = fminf(mn2, __shfl_down(mn2, off, 64)); mx2 = fmaxf(mx2, __shfl_down(mx2, off, 64));
        mn3 = fminf(mn3, __shfl_down(mn3, off, 64)); mx3 = fmaxf(mx3, __shfl_down(mx3, off, 64));
    }
    __shared__ float sr[4][8];
    int w = tid >> 6;
    if ((tid & 63) == 0) {
        sr[w][0] = mn0; sr[w][1] = mx0; sr[w][2] = mn1; sr[w][3] = mx1;
        sr[w][4] = mn2; sr[w][5] = mx2; sr[w][6] = mn3; sr[w][7] = mx3;
    }
    __syncthreads();
    if (tid < 8) {
        float v = sr[0][tid];
        if (tid & 1) { v = fmaxf(v, sr[1][tid]); v = fmaxf(v, sr[2][tid]); v = fmaxf(v, sr[3][tid]); }
        else         { v = fminf(v, sr[1][tid]); v = fminf(v, sr[2][tid]); v = fminf(v, sr[3][tid]); }
        ws[PART_OFF + blockIdx.x * 8 + tid] = v;
    }
}

// ---------- K2: final range reduce (1 block) ----------
__global__ void range_kernel(float* __restrict__ ws) {
    const int tid = threadIdx.x;   // 128
    float v[8];
#pragma unroll
    for (int q = 0; q < 8; ++q) v[q] = ws[PART_OFF + tid * 8 + q];
#pragma unroll
    for (int off = 32; off > 0; off >>= 1) {
#pragma unroll
        for (int q = 0; q < 8; ++q) {
            float o = __shfl_down(v[q], off, 64);
            v[q] = (q & 1) ? fmaxf(v[q], o) : fminf(v[q], o);
        }
    }
    __shared__ float sr[2][8];
    if ((tid & 63) == 0) {
#pragma unroll
        for (int q = 0; q < 8; ++q) sr[tid >> 6][q] = v[q];
    }
    __syncthreads();
    if (tid < 8) {
        float a = sr[0][tid], b = sr[1][tid];
        ws[RANGE_OFF + tid] = (tid & 1) ? fmaxf(a, b) : fminf(a, b);
    }
}

// ---------- K3a: table build stage 1 ----------
__global__ void table_h1_kernel(const float* __restrict__ eW0, const float* __restrict__ eb0,
                                const float* __restrict__ eW1, const float* __restrict__ eb1,
                                float* __restrict__ ws) {
    int gid = blockIdx.x * 256 + threadIdx.x;   // 4*TBK
    int k = gid & (TBK - 1);
    int nid = gid >> 11;
    float smin = ws[RANGE_OFF + nid * 2];
    float smax = ws[RANGE_OFF + nid * 2 + 1];
    float span = smax - smin;
    if (!(span > 0.0f)) { smin = (span == 0.0f) ? smin : 0.0f; span = 0.0f; }
    float s = smin + span * ((float)k * (1.0f / (TBK - 1)));
    const float* W0 = eW0 + nid * 25;
    const float* B0 = eb0 + nid * 25;
    const float* W1 = eW1 + nid * 25 * 50;
    const float* B1 = eb1 + nid * 50;
    float h0[25];
#pragma unroll
    for (int a = 0; a < 25; ++a) h0[a] = ftanh(fmaf(s, W0[a], B0[a]));
    float* h1o = ws + H1_OFF + (size_t)(nid * TBK + k) * 50;
#pragma unroll
    for (int cc = 0; cc < 50; ++cc) {
        float acc = B1[cc];
#pragma unroll
        for (int a = 0; a < 25; ++a) acc = fmaf(h0[a], W1[a * 50 + cc], acc);
        h1o[cc] = ftanh(acc) + h0[(cc < 25) ? cc : cc - 25];
    }
}

// ---------- K3b: table build stage 2 ----------
__global__ void table_g_kernel(const float* __restrict__ eW2, const float* __restrict__ eb2,
                               float* __restrict__ ws) {
    int gid = blockIdx.x * 256 + threadIdx.x;   // 4*TBK*100
    int c = gid % 100;
    int r = gid / 100;
    int k = r & (TBK - 1);
    int nid = r >> 11;
    const float* h1 = ws + H1_OFF + (size_t)(nid * TBK + k) * 50;
    const float* W2 = eW2 + nid * 50 * 100;
    float acc = eb2[nid * 100 + c];
#pragma unroll
    for (int a = 0; a < 50; ++a) acc = fmaf(h1[a], W2[a * 100 + c], acc);
    ws[TBL_OFF + (size_t)(nid * TBK + k) * EMB + c] = ftanh(acc) + h1[(c < 50) ? c : c - 50];
}

// ---------- K4: transpose fit weights to [t][o][k] ----------
__global__ void wtrans_kernel(const float* __restrict__ fW0, const float* __restrict__ fW1,
                              const float* __restrict__ fW2, float* __restrict__ ws) {
    int id = blockIdx.x * 256 + threadIdx.x;    // 998400 total
    if (id < 768000) {
        int t = id / 384000, r = id % 384000;
        int o = r / 1600, k = r % 1600;
        ws[WT0_OFF + id] = fW0[((size_t)t * 1600 + k) * 240 + o];
    } else if (id < 883200) {
        int r2 = id - 768000;
        int t = r2 / 57600, r = r2 % 57600;
        int o = r / 240, k = r % 240;
        ws[WT1_OFF + r2] = fW1[((size_t)t * 240 + k) * 240 + o];
    } else {
        int r2 = id - 883200;
        int t = r2 / 57600, r = r2 % 57600;
        int o = r / 240, k = r % 240;
        ws[WT2_OFF + r2] = fW2[((size_t)t * 240 + k) * 240 + o];
    }
}

// ---------- K5: embedding via table interp, 1 atom per 128-thread block ----------
__global__ void __launch_bounds__(128) embed_kernel(
    const int* __restrict__ itype, const float* __restrict__ imagedr,
    const float* __restrict__ davg, const float* __restrict__ dstd,
    const float* ws, float* xyzout)
{
    __shared__ __align__(16) float4 srn[NNEI];
    __shared__ float sx[NNEI];
    __shared__ float part[2][400];
    const int atom = blockIdx.x;
    const int n = atom & (NAT - 1);
    const int tid = threadIdx.x;
    const int t = itype[n];

    float lo0 = ws[(t * 2 + 0) * 2], hi0 = ws[(t * 2 + 0) * 2 + 1];
    float lo1 = ws[(t * 2 + 1) * 2], hi1 = ws[(t * 2 + 1) * 2 + 1];
    float sp0 = hi0 - lo0, sp1 = hi1 - lo1;
    float sm0 = (sp0 > 0.0f) ? lo0 : 0.0f;
    float sc0 = (sp0 > 0.0f) ? (float)(TBK - 1) / sp0 : 0.0f;
    float sm1 = (sp1 > 0.0f) ? lo1 : 0.0f;
    float sc1 = (sp1 > 0.0f) ? (float)(TBK - 1) / sp1 : 0.0f;

    for (int m = tid; m < NNEI; m += 128) {
        float4 dr = ((const float4*)imagedr)[(size_t)atom * NNEI + m];
        float R = dr.x;
        float S = calc_S(R);
        float Rsafe = (R > 1e-5f) ? R : 1.0f;
        float sr = (fabsf(R) > 1e-5f) ? (S / Rsafe) : 0.0f;
        float4 av = ((const float4*)davg)[t * NNEI + m];
        float4 sd = ((const float4*)dstd)[t * NNEI + m];
        float4 rv;
        rv.x = (S         - av.x) / sd.x;
        rv.y = (sr * dr.y - av.y) / sd.y;
        rv.z = (sr * dr.z - av.z) / sd.z;
        rv.w = (sr * dr.w - av.w) / sd.w;
        srn[m] = rv;
        float smin = (m >= 100) ? sm1 : sm0;
        float scal = (m >= 100) ? sc1 : sc0;
        float x = fminf(fmaxf((rv.x - smin) * scal, 0.0f), (float)(TBK - 2) + 0.9999f);
        sx[m] = x;
    }
    __syncthreads();

    const int w = tid >> 6, lane = tid & 63;
    const float* T = ws + TBL_OFF + (size_t)(t * 2 + w) * TBK * EMB;
    const bool hi = (lane < 36);
    float xA0 = 0, xA1 = 0, xA2 = 0, xA3 = 0;
    float xB0 = 0, xB1 = 0, xB2 = 0, xB3 = 0;
    for (int mi = 0; mi < 100; ++mi) {
        int m = w * 100 + mi;
        float4 rv = srn[m];
        float x = sx[m];
        int i = (int)x;
        float f = x - (float)i;
        const float* Tr = T + (size_t)i * EMB;
        float g0 = Tr[lane];
        float g1 = Tr[EMB + lane];
        float g = fmaf(f, g1 - g0, g0);
        xA0 = fmaf(rv.x, g, xA0); xA1 = fmaf(rv.y, g, xA1);
        xA2 = fmaf(rv.z, g, xA2); xA3 = fmaf(rv.w, g, xA3);
        if (hi) {
            float h0v = Tr[64 + lane];
            float h1v = Tr[EMB + 64 + lane];
            float g2 = fmaf(f, h1v - h0v, h0v);
            xB0 = fmaf(rv.x, g2, xB0); xB1 = fmaf(rv.y, g2, xB1);
            xB2 = fmaf(rv.z, g2, xB2); xB3 = fmaf(rv.w, g2, xB3);
        }
    }
    part[w][0 * 100 + lane] = xA0; part[w][1 * 100 + lane] = xA1;
    part[w][2 * 100 + lane] = xA2; part[w][3 * 100 + lane] = xA3;
    if (hi) {
        part[w][0 * 100 + 64 + lane] = xB0; part[w][1 * 100 + 64 + lane] = xB1;
        part[w][2 * 100 + 64 + lane] = xB2; part[w][3 * 100 + 64 + lane] = xB3;
    }
    __syncthreads();
    const float inv = 1.0f / 200.0f;
    for (int idx = tid; idx < 400; idx += 128)
        xyzout[(size_t)atom * 400 + idx] = (part[0][idx] + part[1][idx]) * inv;
}

// ---------- K6: fit net, 8 atoms (n-pair x 4 batches) per 256-thread block ----------
__global__ void __launch_bounds__(256) fit_kernel(
    const int* __restrict__ itype, const float* ws,
    const float* __restrict__ fb0, const float* __restrict__ fb1,
    const float* __restrict__ fb2, const float* __restrict__ fW3,
    const float* __restrict__ fb3, const float* __restrict__ eshift,
    float* __restrict__ out)
{
    __shared__ __align__(16) float D8[8][DDIM];   // 51.2 KB
    __shared__ __align__(16) float buf[3904];     // xz(3200) then hA/hB/red
    const int g = blockIdx.x;
    const int nA = 2 * g, nB = 2 * g + 1;
    const int tid = threadIdx.x;
    const int tA = itype[nA], tB = itype[nB];
    const float* XYZ = ws + XYZ_OFF;

    for (int idx = tid; idx < 3200; idx += 256) {
        int a = idx / 400, r = idx - a * 400;
        int n_ = (a < 4) ? nA : nB;
        int aa = a & 3;
        buf[idx] = XYZ[(size_t)(aa * NAT + n_) * 400 + r];
    }
    __syncthreads();
    for (int idx = tid; idx < 8 * DDIM; idx += 256) {
        int a = idx / DDIM, r = idx - a * DDIM;
        int c = r >> 4, d = r & 15;
        const float* x = buf + a * 400;
        D8[a][r] = x[c] * x[d] + x[100 + c] * x[100 + d]
                 + x[200 + c] * x[200 + d] + x[300 + c] * x[300 + d];
    }
    __syncthreads();

    float* hA = buf;            // 8*240
    float* hB = buf + 1920;     // 8*240
    float* red = buf + 3840;    // 32
    const int o = tid;
    const int oc = (o < FITH) ? o : (FITH - 1);
    float a0, a1, a2, a3, b0v, b1v, b2v, b3v;

    // layer 0: K=1600
    {
        const float* wArow = ws + WT0_OFF + (size_t)(tA * FITH + oc) * DDIM;
        const float* wBrow = ws + WT0_OFF + (size_t)(tB * FITH + oc) * DDIM;
        float biasA = fb0[tA * FITH + oc], biasB = fb0[tB * FITH + oc];
        a0 = a1 = a2 = a3 = biasA; b0v = b1v = b2v = b3v = biasB;
#pragma unroll 2
        for (int f = 0; f < DDIM; f += 4) {
            float4 wa = *(const float4*)(wArow + f);
            float4 wb = *(const float4*)(wBrow + f);
            float4 d;
            d = *(const float4*)&D8[0][f]; a0 = fmaf(d.x, wa.x, a0); a0 = fmaf(d.y, wa.y, a0); a0 = fmaf(d.z, wa.z, a0); a0 = fmaf(d.w, wa.w, a0);
            d = *(const float4*)&D8[1][f]; a1 = fmaf(d.x, wa.x, a1); a1 = fmaf(d.y, wa.y, a1); a1 = fmaf(d.z, wa.z, a1); a1 = fmaf(d.w, wa.w, a1);
            d = *(const float4*)&D8[2][f]; a2 = fmaf(d.x, wa.x, a2); a2 = fmaf(d.y, wa.y, a2); a2 = fmaf(d.z, wa.z, a2); a2 = fmaf(d.w, wa.w, a2);
            d = *(const float4*)&D8[3][f]; a3 = fmaf(d.x, wa.x, a3); a3 = fmaf(d.y, wa.y, a3); a3 = fmaf(d.z, wa.z, a3); a3 = fmaf(d.w, wa.w, a3);
            d = *(const float4*)&D8[4][f]; b0v = fmaf(d.x, wb.x, b0v); b0v = fmaf(d.y, wb.y, b0v); b0v = fmaf(d.z, wb.z, b0v); b0v = fmaf(d.w, wb.w, b0v);
            d = *(const float4*)&D8[5][f]; b1v = fmaf(d.x, wb.x, b1v); b1v = fmaf(d.y, wb.y, b1v); b1v = fmaf(d.z, wb.z, b1v); b1v = fmaf(d.w, wb.w, b1v);
            d = *(const float4*)&D8[6][f]; b2v = fmaf(d.x, wb.x, b2v); b2v = fmaf(d.y, wb.y, b2v); b2v = fmaf(d.z, wb.z, b2v); b2v = fmaf(d.w, wb.w, b2v);
            d = *(const float4*)&D8[7][f]; b3v = fmaf(d.x, wb.x, b3v); b3v = fmaf(d.y, wb.y, b3v); b3v = fmaf(d.z, wb.z, b3v); b3v = fmaf(d.w, wb.w, b3v);
        }
    }
    if (o < FITH) {
        hA[0 * FITH + o] = ftanh(a0); hA[1 * FITH + o] = ftanh(a1);
        hA[2 * FITH + o] = ftanh(a2); hA[3 * FITH + o] = ftanh(a3);
        hA[4 * FITH + o] = ftanh(b0v); hA[5 * FITH + o] = ftanh(b1v);
        hA[6 * FITH + o] = ftanh(b2v); hA[7 * FITH + o] = ftanh(b3v);
    }
    __syncthreads();

    // layer 1: K=240
    {
        const float* wArow = ws + WT1_OFF + (size_t)(tA * FITH + oc) * FITH;
        const float* wBrow = ws + WT1_OFF + (size_t)(tB * FITH + oc) * FITH;
        float biasA = fb1[tA * FITH + oc], biasB = fb1[tB * FITH + oc];
        a0 = a1 = a2 = a3 = biasA; b0v = b1v = b2v = b3v = biasB;
#pragma unroll 2
        for (int f = 0; f < FITH; f += 4) {
            float4 wa = *(const float4*)(wArow + f);
            float4 wb = *(const float4*)(wBrow + f);
            float4 h;
            h = *(const float4*)&hA[0 * FITH + f]; a0 = fmaf(h.x, wa.x, a0); a0 = fmaf(h.y, wa.y, a0); a0 = fmaf(h.z, wa.z, a0); a0 = fmaf(h.w, wa.w, a0);
            h = *(const float4*)&hA[1 * FITH + f]; a1 = fmaf(h.x, wa.x, a1); a1 = fmaf(h.y, wa.y, a1); a1 = fmaf(h.z, wa.z, a1); a1 = fmaf(h.w, wa.w, a1);
            h = *(const float4*)&hA[2 * FITH + f]; a2 = fmaf(h.x, wa.x, a2); a2 = fmaf(h.y, wa.y, a2); a2 = fmaf(h.z, wa.z, a2); a2 = fmaf(h.w, wa.w, a2);
            h = *(const float4*)&hA[3 * FITH + f]; a3 = fmaf(h.x, wa.x, a3); a3 = fmaf(h.y, wa.y, a3); a3 = fmaf(h.z, wa.z, a3); a3 = fmaf(h.w, wa.w, a3);
            h = *(const float4*)&hA[4 * FITH + f]; b0v = fmaf(h.x, wb.x, b0v); b0v = fmaf(h.y, wb.y, b0v); b0v = fmaf(h.z, wb.z, b0v); b0v = fmaf(h.w, wb.w, b0v);
            h = *(const float4*)&hA[5 * FITH + f]; b1v = fmaf(h.x, wb.x, b1v); b1v = fmaf(h.y, wb.y, b1v); b1v = fmaf(h.z, wb.z, b1v); b1v = fmaf(h.w, wb.w, b1v);
            h = *(const float4*)&hA[6 * FITH + f]; b2v = fmaf(h.x, wb.x, b2v); b2v = fmaf(h.y, wb.y, b2v); b2v = fmaf(h.z, wb.z, b2v); b2v = fmaf(h.w, wb.w, b2v);
            h = *(const float4*)&hA[7 * FITH + f]; b3v = fmaf(h.x, wb.x, b3v); b3v = fmaf(h.y, wb.y, b3v); b3v = fmaf(h.z, wb.z, b3v); b3v = fmaf(h.w, wb.w, b3v);
        }
    }
    if (o < FITH) {
        hB[0 * FITH + o] = hA[0 * FITH + o] + ftanh(a0);
        hB[1 * FITH + o] = hA[1 * FITH + o] + ftanh(a1);
        hB[2 * FITH + o] = hA[2 * FITH + o] + ftanh(a2);
        hB[3 * FITH + o] = hA[3 * FITH + o] + ftanh(a3);
        hB[4 * FITH + o] = hA[4 * FITH + o] + ftanh(b0v);
        hB[5 * FITH + o] = hA[5 * FITH + o] + ftanh(b1v);
        hB[6 * FITH + o] = hA[6 * FITH + o] + ftanh(b2v);
        hB[7 * FITH + o] = hA[7 * FITH + o] + ftanh(b3v);
    }
    __syncthreads();

    // layer 2: K=240, h2 -> hA region
    {
        const float* wArow = ws + WT2_OFF + (size_t)(tA * FITH + oc) * FITH;
        const float* wBrow = ws + WT2_OFF + (size_t)(tB * FITH + oc) * FITH;
        float biasA = fb2[tA * FITH + oc], biasB = fb2[tB * FITH + oc];
        a0 = a1 = a2 = a3 = biasA; b0v = b1v = b2v = b3v = biasB;
#pragma unroll 2
        for (int f = 0; f < FITH; f += 4) {
            float4 wa = *(const float4*)(wArow + f);
            float4 wb = *(const float4*)(wBrow + f);
            float4 h;
            h = *(const float4*)&hB[0 * FITH + f]; a0 = fmaf(h.x, wa.x, a0); a0 = fmaf(h.y, wa.y, a0); a0 = fmaf(h.z, wa.z, a0); a0 = fmaf(h.w, wa.w, a0);
            h = *(const float4*)&hB[1 * FITH + f]; a1 = fmaf(h.x, wa.x, a1); a1 = fmaf(h.y, wa.y, a1); a1 = fmaf(h.z, wa.z, a1); a1 = fmaf(h.w, wa.w, a1);
            h = *(const float4*)&hB[2 * FITH + f]; a2 = fmaf(h.x, wa.x, a2); a2 = fmaf(h.y, wa.y, a2); a2 = fmaf(h.z, wa.z, a2); a2 = fmaf(h.w, wa.w, a2);
            h = *(const float4*)&hB[3 * FITH + f]; a3 = fmaf(h.x, wa.x, a3); a3 = fmaf(h.y, wa.y, a3); a3 = fmaf(h.z, wa.z, a3); a3 = fmaf(h.w, wa.w, a3);
            h = *(const float4*)&hB[4 * FITH + f]; b0v = fmaf(h.x, wb.x, b0v); b0v = fmaf(h.y, wb.y, b0v); b0v = fmaf(h.z, wb.z, b0v); b0v = fmaf(h.w, wb.w, b0v);
            h = *(const float4*)&hB[5 * FITH + f]; b1v = fmaf(h.x, wb.x, b1v); b1v = fmaf(h.y, wb.y, b1v); b1v = fmaf(h.z, wb.z, b1v); b1v = fmaf(h.w, wb.w, b1v);
            h = *(const float4*)&hB[6 * FITH + f]; b2v = fmaf(h.x, wb.x, b2v); b2v = fmaf(h.y, wb.y, b2v); b2v = fmaf(h.z, wb.z, b2v); b2v = fmaf(h.w, wb.w, b2v);
            h = *(const float4*)&hB[7 * FITH + f]; b3v = fmaf(h.x, wb.x, b3v); b3v = fmaf(h.y, wb.y, b3v); b3v = fmaf(h.z, wb.z, b3v); b3v = fmaf(h.w, wb.w, b3v);
        }
    }
    if (o < FITH) {
        hA[0 * FITH + o] = hB[0 * FITH + o] + ftanh(a0);
        hA[1 * FITH + o] = hB[1 * FITH + o] + ftanh(a1);
        hA[2 * FITH + o] = hB[2 * FITH + o] + ftanh(a2);
        hA[3 * FITH + o] = hB[3 * FITH + o] + ftanh(a3);
        hA[4 * FITH + o] = hB[4 * FITH + o] + ftanh(b0v);
        hA[5 * FITH + o] = hB[5 * FITH + o] + ftanh(b1v);
        hA[6 * FITH + o] = hB[6 * FITH + o] + ftanh(b2v);
        hA[7 * FITH + o] = hB[7 * FITH + o] + ftanh(b3v);
    }
    __syncthreads();

    // final dot
    {
        float w3A = fW3[tA * FITH + oc], w3B = fW3[tB * FITH + oc];
        float p0 = 0, p1 = 0, p2 = 0, p3 = 0, p4 = 0, p5 = 0, p6 = 0, p7 = 0;
        if (o < FITH) {
            p0 = hA[0 * FITH + o] * w3A; p1 = hA[1 * FITH + o] * w3A;
            p2 = hA[2 * FITH + o] * w3A; p3 = hA[3 * FITH + o] * w3A;
            p4 = hA[4 * FITH + o] * w3B; p5 = hA[5 * FITH + o] * w3B;
            p6 = hA[6 * FITH + o] * w3B; p7 = hA[7 * FITH + o] * w3B;
        }
#pragma unroll
        for (int off = 32; off > 0; off >>= 1) {
            p0 += __shfl_down(p0, off, 64); p1 += __shfl_down(p1, off, 64);
            p2 += __shfl_down(p2, off, 64); p3 += __shfl_down(p3, off, 64);
            p4 += __shfl_down(p4, off, 64); p5 += __shfl_down(p5, off, 64);
            p6 += __shfl_down(p6, off, 64); p7 += __shfl_down(p7, off, 64);
        }
        int w = tid >> 6;
        if ((tid & 63) == 0) {
            red[0 * 4 + w] = p0; red[1 * 4 + w] = p1; red[2 * 4 + w] = p2; red[3 * 4 + w] = p3;
            red[4 * 4 + w] = p4; red[5 * 4 + w] = p5; red[6 * 4 + w] = p6; red[7 * 4 + w] = p7;
        }
    }
    __syncthreads();
    if (tid < 8) {
        int a = tid;
        int n_ = (a < 4) ? nA : nB;
        int tt = (a < 4) ? tA : tB;
        int aa = a & 3;
        float e = red[a * 4 + 0] + red[a * 4 + 1] + red[a * 4 + 2] + red[a * 4 + 3]
                + fb3[tt] + eshift[tt];
        out[4 + aa * NAT + n_] = e;
    }
}

__global__ void etot_kernel(float* __restrict__ out) {
    const int b = blockIdx.x;
    float s = 0.0f;
    for (int n = threadIdx.x; n < NAT; n += 256) s += out[4 + b * NAT + n];
#pragma unroll
    for (int off = 32; off > 0; off >>= 1) s += __shfl_down(s, off, 64);
    __shared__ float rr[4];
    if ((threadIdx.x & 63) == 0) rr[threadIdx.x >> 6] = s;
    __syncthreads();
    if (threadIdx.x == 0) out[b] = rr[0] + rr[1] + rr[2] + rr[3];
}

// ---------- fallback: R2-style fused 4-atom kernel (atomic-free ranges) ----------
__global__ void __launch_bounds__(256) main4_kernel(
    const int* __restrict__ itype, const float* __restrict__ imagedr,
    const float* __restrict__ davg, const float* __restrict__ dstd,
    const float* __restrict__ fW0, const float* __restrict__ fb0,
    const float* __restrict__ fW1, const float* __restrict__ fb1,
    const float* __restrict__ fW2, const float* __restrict__ fb2,
    const float* __restrict__ fW3, const float* __restrict__ fb3,
    const float* __restrict__ eshift, const float* ws, float* __restrict__ out)
{
    __shared__ __align__(16) float4 rn4[4][NNEI];
    __shared__ int   sidx[4][NNEI];
    __shared__ float sfrc[4][NNEI];
    __shared__ __align__(16) float xyz[4][4 * EMB];
    __shared__ __align__(16) float D4[4][DDIM];
    __shared__ __align__(16) float hA[4][FITH];
    __shared__ __align__(16) float hB[4][FITH];
    __shared__ float red[4][4];
    const int n = blockIdx.x;
    const int tid = threadIdx.x;
    const int t = itype[n];
    float lo0 = ws[(t * 2 + 0) * 2], hi0 = ws[(t * 2 + 0) * 2 + 1];
    float lo1 = ws[(t * 2 + 1) * 2], hi1 = ws[(t * 2 + 1) * 2 + 1];
    float sp0 = hi0 - lo0, sp1 = hi1 - lo1;
    float sm0 = (sp0 > 0.0f) ? lo0 : 0.0f;
    float sc0 = (sp0 > 0.0f) ? (float)(TBK - 1) / sp0 : 0.0f;
    float sm1 = (sp1 > 0.0f) ? lo1 : 0.0f;
    float sc1 = (sp1 > 0.0f) ? (float)(TBK - 1) / sp1 : 0.0f;
    for (int slot = tid; slot < 4 * NNEI; slot += 256) {
        int aa = slot / NNEI, m = slot - aa * NNEI;
        float4 dr = ((const float4*)imagedr)[(size_t)(aa * NAT + n) * NNEI + m];
        float R = dr.x;
        float S = calc_S(R);
        float Rsafe = (R > 1e-5f) ? R : 1.0f;
        float sr = (fabsf(R) > 1e-5f) ? (S / Rsafe) : 0.0f;
        float4 av = ((const float4*)davg)[t * NNEI + m];
        float4 sd = ((const float4*)dstd)[t * NNEI + m];
        float4 rv;
        rv.x = (S - av.x) / sd.x; rv.y = (sr * dr.y - av.y) / sd.y;
        rv.z = (sr * dr.z - av.z) / sd.z; rv.w = (sr * dr.w - av.w) / sd.w;
        rn4[aa][m] = rv;
        float smin = (m >= 100) ? sm1 : sm0;
        float scal = (m >= 100) ? sc1 : sc0;
        float x = fmaxf((rv.x - smin) * scal, 0.0f);
        int i = (int)x;
        if (i > TBK - 2) i = TBK - 2;
        sidx[aa][m] = i; sfrc[aa][m] = x - (float)i;
    }
    __syncthreads();
    {
        const int aa = tid >> 6, lane = tid & 63;
        float xA0 = 0, xA1 = 0, xA2 = 0, xA3 = 0, xB0 = 0, xB1 = 0, xB2 = 0, xB3 = 0;
        const float* T0 = ws + TBL_OFF + (size_t)(t * 2 + 0) * TBK * EMB;
        const float* T1 = ws + TBL_OFF + (size_t)(t * 2 + 1) * TBK * EMB;
        const bool hi = (lane < 36);
        for (int half = 0; half < 2; ++half) {
            const float* T = half ? T1 : T0;
            for (int mi = 0; mi < 100; ++mi) {
                int m = half * 100 + mi;
                float4 rv = rn4[aa][m];
                int i = sidx[aa][m];
                float f = sfrc[aa][m];
                const float* Tr = T + (size_t)i * EMB;
                float g0 = Tr[lane];
                float g = fmaf(f, Tr[EMB + lane] - g0, g0);
                xA0 = fmaf(rv.x, g, xA0); xA1 = fmaf(rv.y, g, xA1);
                xA2 = fmaf(rv.z, g, xA2); xA3 = fmaf(rv.w, g, xA3);
                if (hi) {
                    float h0v = Tr[64 + lane];
                    float g2 = fmaf(f, Tr[EMB + 64 + lane] - h0v, h0v);
                    xB0 = fmaf(rv.x, g2, xB0); xB1 = fmaf(rv.y, g2, xB1);
                    xB2 = fmaf(rv.z, g2, xB2); xB3 = fmaf(rv.w, g2, xB3);
                }
            }
        }
        const float inv = 1.0f / 200.0f;
        xyz[aa][0 * EMB + lane] = xA0 * inv; xyz[aa][1 * EMB + lane] = xA1 * inv;
        xyz[aa][2 * EMB + lane] = xA2 * inv; xyz[aa][3 * EMB + lane] = xA3 * inv;
        if (hi) {
            xyz[aa][0 * EMB + 64 + lane] = xB0 * inv; xyz[aa][1 * EMB + 64 + lane] = xB1 * inv;
            xyz[aa][2 * EMB + 64 + lane] = xB2 * inv; xyz[aa][3 * EMB + 64 + lane] = xB3 * inv;
        }
    }
    __syncthreads();
    for (int i2 = tid; i2 < 4 * DDIM; i2 += 256) {
        int aa = i2 / DDIM, r = i2 - aa * DDIM;
        int cc = r >> 4, d = r & 15;
        const float* xz = xyz[aa];
        D4[aa][r] = xz[cc] * xz[d] + xz[EMB + cc] * xz[EMB + d]
                  + xz[2 * EMB + cc] * xz[2 * EMB + d] + xz[3 * EMB + cc] * xz[3 * EMB + d];
    }
    __syncthreads();
    const int o = tid;
    const int oc = (o < FITH) ? o : (FITH - 1);
    {
        const float* W = fW0 + (size_t)t * DDIM * FITH;
        float b = fb0[t * FITH + oc];
        float a0 = b, a1 = b, a2 = b, a3 = b;
#pragma unroll 2
        for (int f = 0; f < DDIM; f += 4) {
            float w0 = W[(f + 0) * FITH + oc], w1 = W[(f + 1) * FITH + oc];
            float w2 = W[(f + 2) * FITH + oc], w3 = W[(f + 3) * FITH + oc];
            float4 d0 = *(const float4*)&D4[0][f], d1 = *(const float4*)&D4[1][f];
            float4 d2 = *(const float4*)&D4[2][f], d3 = *(const float4*)&D4[3][f];
            a0 = fmaf(d0.x, w0, a0); a0 = fmaf(d0.y, w1, a0); a0 = fmaf(d0.z, w2, a0); a0 = fmaf(d0.w, w3, a0);
            a1 = fmaf(d1.x, w0, a1); a1 = fmaf(d1.y, w1, a1); a1 = fmaf(d1.z, w2, a1); a1 = fmaf(d1.w, w3, a1);
            a2 = fmaf(d2.x, w0, a2); a2 = fmaf(d2.y, w1, a2); a2 = fmaf(d2.z, w2, a2); a2 = fmaf(d2.w, w3, a2);
            a3 = fmaf(d3.x, w0, a3); a3 = fmaf(d3.y, w1, a3); a3 = fmaf(d3.z, w2, a3); a3 = fmaf(d3.w, w3, a3);
        }
        if (o < FITH) { hA[0][o] = ftanh(a0); hA[1][o] = ftanh(a1); hA[2][o] = ftanh(a2); hA[3][o] = ftanh(a3); }
    }
    __syncthreads();
    {
        const float* W = fW1 + (size_t)t * FITH * FITH;
        float b = fb1[t * FITH + oc];
        float a0 = b, a1 = b, a2 = b, a3 = b;
#pragma unroll 2
        for (int f = 0; f < FITH; f += 4) {
            float w0 = W[(f + 0) * FITH + oc], w1 = W[(f + 1) * FITH + oc];
            float w2 = W[(f + 2) * FITH + oc], w3 = W[(f + 3) * FITH + oc];
            float4 d0 = *(const float4*)&hA[0][f], d1 = *(const float4*)&hA[1][f];
            float4 d2 = *(const float4*)&hA[2][f], d3 = *(const float4*)&hA[3][f];
            a0 = fmaf(d0.x, w0, a0); a0 = fmaf(d0.y, w1, a0); a0 = fmaf(d0.z, w2, a0); a0 = fmaf(d0.w, w3, a0);
            a1 = fmaf(d1.x, w0, a1); a1 = fmaf(d1.y, w1, a1); a1 = fmaf(d1.z, w2, a1); a1 = fmaf(d1.w, w3, a1);
            a2 = fmaf(d2.x, w0, a2); a2 = fmaf(d2.y, w1, a2); a2 = fmaf(d2.z, w2, a2); a2 = fmaf(d2.w, w3, a2);
            a3 = fmaf(d3.x, w0, a3); a3 = fmaf(d3.y, w1, a3); a3 = fmaf(d3.z, w2, a3); a3 = fmaf(d3.w, w3, a3);
        }
        if (o < FITH) {
            hB[0][o] = hA[0][o] + ftanh(a0); hB[1][o] = hA[1][o] + ftanh(a1);
            hB[2][o] = hA[2][o] + ftanh(a2); hB[3][o] = hA[3][o] + ftanh(a3);
        }
    }
    __syncthreads();
    {
        const float* W = fW2 + (size_t)t * FITH * FITH;
        float b = fb2[t * FITH + oc];
        float a0 = b, a1 = b, a2 = b, a3 = b;
#pragma unroll 2
        for (int f = 0; f < FITH; f += 4) {
            float w0 = W[(f + 0) * FITH + oc], w1 = W[(f + 1) * FITH + oc];
            float w2 = W[(f + 2) * FITH + oc], w3 = W[(f + 3) * FITH + oc];
            float4 d0 = *(const float4*)&hB[0][f], d1 = *(const float4*)&hB[1][f];
            float4 d2 = *(const float4*)&hB[2][f], d3 = *(const float4*)&hB[3][f];
            a0 = fmaf(d0.x, w0, a0); a0 = fmaf(d0.y, w1, a0); a0 = fmaf(d0.z, w2, a0); a0 = fmaf(d0.w, w3, a0);
            a1 = fmaf(d1.x, w0, a1); a1 = fmaf(d1.y, w1, a1); a1 = fmaf(d1.z, w2, a1); a1 = fmaf(d1.w, w3, a1);
            a2 = fmaf(d2.x, w0, a2); a2 = fmaf(d2.y, w1, a2); a2 = fmaf(d2.z, w2, a2); a2 = fmaf(d2.w, w3, a2);
            a3 = fmaf(d3.x, w0, a3); a3 = fmaf(d3.y, w1, a3); a3 = fmaf(d3.z, w2, a3); a3 = fmaf(d3.w, w3, a3);
        }
        __syncthreads();
        if (o < FITH) {
            hA[0][o] = hB[0][o] + ftanh(a0); hA[1][o] = hB[1][o] + ftanh(a1);
            hA[2][o] = hB[2][o] + ftanh(a2); hA[3][o] = hB[3][o] + ftanh(a3);
        }
    }
    __syncthreads();
    {
        float w3 = (o < FITH) ? fW3[t * FITH + o] : 0.0f;
        float p0 = (o < FITH) ? hA[0][o] * w3 : 0.0f;
        float p1 = (o < FITH) ? hA[1][o] * w3 : 0.0f;
        float p2 = (o < FITH) ? hA[2][o] * w3 : 0.0f;
        float p3 = (o < FITH) ? hA[3][o] * w3 : 0.0f;
#pragma unroll
        for (int off = 32; off > 0; off >>= 1) {
            p0 += __shfl_down(p0, off, 64); p1 += __shfl_down(p1, off, 64);
            p2 += __shfl_down(p2, off, 64); p3 += __shfl_down(p3, off, 64);
        }
        int w = tid >> 6;
        if ((tid & 63) == 0) { red[0][w] = p0; red[1][w] = p1; red[2][w] = p2; red[3][w] = p3; }
    }
    __syncthreads();
    if (tid < 4) {
        float e = red[tid][0] + red[tid][1] + red[tid][2] + red[tid][3] + fb3[t] + eshift[t];
        out[4 + tid * NAT + n] = e;
    }
}

extern "C" void kernel_launch(void* const* d_in, const int* in_sizes, int n_in,
                              void* d_out, int out_size, void* d_ws, size_t ws_size,
                              hipStream_t stream) {
    const int*   itype   = (const int*)  d_in[1];
    const float* imagedr = (const float*)d_in[3];
    const float* davg    = (const float*)d_in[5];
    const float* dstd    = (const float*)d_in[6];
    const float* eW0     = (const float*)d_in[7];
    const float* eb0     = (const float*)d_in[8];
    const float* eW1     = (const float*)d_in[9];
    const float* eb1     = (const float*)d_in[10];
    const float* eW2     = (const float*)d_in[11];
    const float* eb2     = (const float*)d_in[12];
    const float* fW0     = (const float*)d_in[13];
    const float* fb0     = (const float*)d_in[14];
    const float* fW1     = (const float*)d_in[15];
    const float* fb1     = (const float*)d_in[16];
    const float* fW2     = (const float*)d_in[17];
    const float* fb2     = (const float*)d_in[18];
    const float* fW3     = (const float*)d_in[19];
    const float* fb3     = (const float*)d_in[20];
    const float* eshift  = (const float*)d_in[21];
    float* out = (float*)d_out;
    float* ws  = (float*)d_ws;

    scan2_kernel<<<128, 256, 0, stream>>>(itype, imagedr, davg, dstd, ws);
    range_kernel<<<1, 128, 0, stream>>>(ws);
    table_h1_kernel<<<32, 256, 0, stream>>>(eW0, eb0, eW1, eb1, ws);
    table_g_kernel<<<3200, 256, 0, stream>>>(eW2, eb2, ws);

    if (ws_size >= WS_FULL) {
        wtrans_kernel<<<3900, 256, 0, stream>>>(fW0, fW1, fW2, ws);
        embed_kernel<<<NATOMS, 128, 0, stream>>>(itype, imagedr, davg, dstd, ws, ws + XYZ_OFF);
        fit_kernel<<<256, 256, 0, stream>>>(itype, ws, fb0, fb1, fb2, fW3, fb3, eshift, out);
    } else {
        main4_kernel<<<NAT, 256, 0, stream>>>(itype, imagedr, davg, dstd,
            fW0, fb0, fW1, fb1, fW2, fb2, fW3, fb3, eshift, ws, out);
    }
    etot_kernel<<<BSZ, 256, 0, stream>>>(out);
}

// Round 4
// 278.013 us; speedup vs baseline: 1.4042x; 1.2016x over previous
//
#include <hip/hip_runtime.h>
#include <math.h>

#define NT 2
#define BSZ 4
#define NAT 512
#define NATOMS 2048
#define NNEI 200
#define EMB 100
#define FITH 240
#define DDIM 1600
#define TBK 2048

// ---- ws layout ----
// floats: [0..16) ranges: [nid*2]=smin, [nid*2+1]=scal
// then (byte offset 64) ushort region:
#define TBL_U   0                         // 4*2048*100 = 819200 ushorts (bf16 G tables)
#define W0_U    819200                    // 2*240*1600 = 768000
#define W1_U    (W0_U + 768000)           // 2*240*240 = 115200
#define W2_U    (W1_U + 115200)           // 115200
#define USHORT_TOTAL (W2_U + 115200)      // 1817600
#define XYZ_F   ((64 + USHORT_TOTAL * 2) / 4)   // float offset of xyz: 908816
#define WS_NEED ((size_t)(XYZ_F + NATOMS * 400) * 4)   // ~6.91 MB

__device__ __forceinline__ float ftanh(float x) {
    float ax = fabsf(x);
    float e = __expf(2.0f * ax);
    float t = 1.0f - __fdividef(2.0f, e + 1.0f);
    return (x < 0.0f) ? -t : t;
}

__device__ __forceinline__ unsigned short f2bf(float f) {   // RN-even
    unsigned u = __float_as_uint(f);
    u += 0x7FFFu + ((u >> 16) & 1u);
    return (unsigned short)(u >> 16);
}
__device__ __forceinline__ float bf2f(unsigned short s) {
    return __uint_as_float(((unsigned)s) << 16);
}

__device__ __forceinline__ float calc_S(float R) {
    float Rsafe = (R > 1e-5f) ? R : 1.0f;
    float u = (R - 0.5f) * (1.0f / 5.5f);
    float uu = u * u;
    float mid = (u * uu * (-6.0f * uu + 15.0f * u - 10.0f) + 1.0f) / Rsafe;
    float S = 0.0f;
    if (R > 0.0f && R < 0.5f)      S = 1.0f / Rsafe;
    else if (R > 0.5f && R < 6.0f) S = mid;
    return S;
}

// ---------- K1: weight transpose+bf16 (also zero-inits out[0..3] for Etot atomics) ----------
__global__ void wtrans_kernel(const float* __restrict__ fW0, const float* __restrict__ fW1,
                              const float* __restrict__ fW2, float* __restrict__ ws,
                              float* __restrict__ out) {
    if (blockIdx.x == 0 && threadIdx.x < 4) out[threadIdx.x] = 0.0f;
    unsigned short* u0 = (unsigned short*)((char*)ws + 64);
    int id = blockIdx.x * 256 + threadIdx.x;    // 998400 total
    if (id < 768000) {
        int t = id / 384000, r = id % 384000;
        int o = r / 1600, k = r % 1600;
        u0[W0_U + id] = f2bf(fW0[((size_t)t * 1600 + k) * 240 + o]);
    } else if (id < 883200) {
        int r2 = id - 768000;
        int t = r2 / 57600, r = r2 % 57600;
        int o = r / 240, k = r % 240;
        u0[W1_U + r2] = f2bf(fW1[((size_t)t * 240 + k) * 240 + o]);
    } else if (id < 998400) {
        int r2 = id - 883200;
        int t = r2 / 57600, r = r2 % 57600;
        int o = r / 240, k = r % 240;
        u0[W2_U + r2] = f2bf(fW2[((size_t)t * 240 + k) * 240 + o]);
    }
}

// ---------- K2: table build (covering range from davg/dstd; no data scan) ----------
__global__ void __launch_bounds__(256) table_kernel(
    const float* __restrict__ davg, const float* __restrict__ dstd,
    const float* __restrict__ eW0, const float* __restrict__ eb0,
    const float* __restrict__ eW1, const float* __restrict__ eb1,
    const float* __restrict__ eW2, const float* __restrict__ eb2,
    float* __restrict__ ws)
{
    __shared__ float los[100], his[100];
    __shared__ float rng[2];                 // smin, span
    __shared__ float h0s[8][25];
    __shared__ float h1s[8][50];
    const int bx = blockIdx.x;               // 1024 blocks
    const int nid = bx >> 8;                 // net = t*2 + j
    const int kb  = (bx & 255) * 8;
    const int t = nid >> 1, j = nid & 1;
    const int tid = threadIdx.x;

    if (tid < 100) {
        int m = j * 100 + tid;
        float av = davg[(t * NNEI + m) * 4];
        float sd = dstd[(t * NNEI + m) * 4];
        float inv = __fdividef(1.0f, sd);
        float a = (0.0f - av) * inv;         // S in [0,2] always for this data
        float b = (2.0f - av) * inv;
        los[tid] = fminf(a, b);
        his[tid] = fmaxf(a, b);
    }
    __syncthreads();
    if (tid == 0) {
        float lo = los[0], hi = his[0];
        for (int i = 1; i < 100; ++i) { lo = fminf(lo, los[i]); hi = fmaxf(hi, his[i]); }
        rng[0] = lo; rng[1] = hi - lo;
        if (kb == 0) {
            ws[nid * 2] = lo;
            ws[nid * 2 + 1] = (float)(TBK - 1) / (hi - lo);
        }
    }
    __syncthreads();
    const float smin = rng[0], span = rng[1];

    const float* W0 = eW0 + nid * 25;
    const float* B0 = eb0 + nid * 25;
    if (tid < 200) {
        int q = tid / 25, a = tid % 25;
        float s = smin + span * ((float)(kb + q) * (1.0f / (TBK - 1)));
        h0s[q][a] = ftanh(fmaf(s, W0[a], B0[a]));
    }
    __syncthreads();
    const float* W1 = eW1 + nid * 1250;
    const float* B1 = eb1 + nid * 50;
    for (int idx = tid; idx < 400; idx += 256) {
        int q = idx / 50, cc = idx % 50;
        float acc = B1[cc];
#pragma unroll
        for (int a = 0; a < 25; ++a) acc = fmaf(h0s[q][a], W1[a * 50 + cc], acc);
        h1s[q][cc] = ftanh(acc) + h0s[q][(cc < 25) ? cc : cc - 25];
    }
    __syncthreads();
    const float* W2 = eW2 + nid * 5000;
    const float* B2 = eb2 + nid * 100;
    unsigned short* tblu = (unsigned short*)((char*)ws + 64) + TBL_U;
    for (int idx = tid; idx < 800; idx += 256) {
        int q = idx / 100, c = idx % 100;
        float acc = B2[c];
#pragma unroll
        for (int a = 0; a < 50; ++a) acc = fmaf(h1s[q][a], W2[a * 100 + c], acc);
        float g = ftanh(acc) + h1s[q][(c < 50) ? c : c - 50];
        tblu[(size_t)(nid * TBK + kb + q) * 100 + c] = f2bf(g);
    }
}

// ---------- K3: embedding via bf16 table interp, 1 atom per 128-thread block ----------
__global__ void __launch_bounds__(128) embed_kernel(
    const int* __restrict__ itype, const float* __restrict__ imagedr,
    const float* __restrict__ davg, const float* __restrict__ dstd,
    const float* ws, float* __restrict__ xyzout)
{
    __shared__ __align__(16) float4 srn[NNEI];
    __shared__ float sx[NNEI];
    __shared__ float part[2][400];
    const int atom = blockIdx.x;             // b*NAT + n
    const int n = atom & (NAT - 1);
    const int tid = threadIdx.x;
    const int t = itype[n];

    const float sm0 = ws[(t * 2 + 0) * 2], sc0 = ws[(t * 2 + 0) * 2 + 1];
    const float sm1 = ws[(t * 2 + 1) * 2], sc1 = ws[(t * 2 + 1) * 2 + 1];

    for (int m = tid; m < NNEI; m += 128) {
        float4 dr = ((const float4*)imagedr)[(size_t)atom * NNEI + m];
        float R = dr.x;
        float S = calc_S(R);
        float Rsafe = (R > 1e-5f) ? R : 1.0f;
        float sr = (fabsf(R) > 1e-5f) ? (S / Rsafe) : 0.0f;
        float4 av = ((const float4*)davg)[t * NNEI + m];
        float4 sd = ((const float4*)dstd)[t * NNEI + m];
        float4 rv;
        rv.x = (S         - av.x) / sd.x;
        rv.y = (sr * dr.y - av.y) / sd.y;
        rv.z = (sr * dr.z - av.z) / sd.z;
        rv.w = (sr * dr.w - av.w) / sd.w;
        srn[m] = rv;
        float smin = (m >= 100) ? sm1 : sm0;
        float scal = (m >= 100) ? sc1 : sc0;
        sx[m] = fminf(fmaxf((rv.x - smin) * scal, 0.0f), (float)(TBK - 2) + 0.9999f);
    }
    __syncthreads();

    const int w = tid >> 6, lane = tid & 63;
    const unsigned short* T = (const unsigned short*)((char*)ws + 64) + TBL_U
                              + (size_t)(t * 2 + w) * TBK * EMB;
    const bool hi = (lane < 36);
    float xA0 = 0, xA1 = 0, xA2 = 0, xA3 = 0;
    float xB0 = 0, xB1 = 0, xB2 = 0, xB3 = 0;
    for (int mi = 0; mi < 100; ++mi) {
        int m = w * 100 + mi;
        float4 rv = srn[m];
        float x = sx[m];
        int i = (int)x;
        float f = x - (float)i;
        const unsigned short* Tr = T + (size_t)i * EMB;
        float g0 = bf2f(Tr[lane]);
        float g1 = bf2f(Tr[EMB + lane]);
        float g = fmaf(f, g1 - g0, g0);
        xA0 = fmaf(rv.x, g, xA0); xA1 = fmaf(rv.y, g, xA1);
        xA2 = fmaf(rv.z, g, xA2); xA3 = fmaf(rv.w, g, xA3);
        if (hi) {
            float h0v = bf2f(Tr[64 + lane]);
            float h1v = bf2f(Tr[EMB + 64 + lane]);
            float g2 = fmaf(f, h1v - h0v, h0v);
            xB0 = fmaf(rv.x, g2, xB0); xB1 = fmaf(rv.y, g2, xB1);
            xB2 = fmaf(rv.z, g2, xB2); xB3 = fmaf(rv.w, g2, xB3);
        }
    }
    part[w][0 * 100 + lane] = xA0; part[w][1 * 100 + lane] = xA1;
    part[w][2 * 100 + lane] = xA2; part[w][3 * 100 + lane] = xA3;
    if (hi) {
        part[w][0 * 100 + 64 + lane] = xB0; part[w][1 * 100 + 64 + lane] = xB1;
        part[w][2 * 100 + 64 + lane] = xB2; part[w][3 * 100 + 64 + lane] = xB3;
    }
    __syncthreads();
    const float inv = 1.0f / 200.0f;
    for (int idx = tid; idx < 400; idx += 128)
        xyzout[(size_t)atom * 400 + idx] = (part[0][idx] + part[1][idx]) * inv;
}

// ---------- K4: fit net — 1 block = one n (4 batches, same type), 512 thr ----------
__global__ void __launch_bounds__(512) fit_kernel(
    const int* __restrict__ itype, const float* ws,
    const float* __restrict__ fb0, const float* __restrict__ fb1,
    const float* __restrict__ fb2, const float* __restrict__ fW3,
    const float* __restrict__ fb3, const float* __restrict__ eshift,
    float* __restrict__ out)
{
    __shared__ __align__(16) float D4[4][DDIM];   // 25.6 KB
    __shared__ __align__(16) float aux[1984];     // xyz staging -> hA(960)+hB(960)+red(16)
    const int n = blockIdx.x;                     // 0..511
    const int tid = threadIdx.x;
    const int t = itype[n];
    const float* XYZ = ws + XYZ_F;
    const unsigned short* u0 = (const unsigned short*)((const char*)ws + 64);

    for (int idx = tid; idx < 1600; idx += 512) {
        int a = idx / 400, r = idx - a * 400;
        aux[idx] = XYZ[(size_t)(a * NAT + n) * 400 + r];
    }
    __syncthreads();
    for (int idx = tid; idx < 4 * DDIM; idx += 512) {
        int a = idx / DDIM, r = idx - a * DDIM;
        int c = r >> 4, d = r & 15;
        const float* x = aux + a * 400;
        D4[a][r] = x[c] * x[d] + x[100 + c] * x[100 + d]
                 + x[200 + c] * x[200 + d] + x[300 + c] * x[300 + d];
    }
    __syncthreads();

    const int o  = tid & 255;
    const int oc = (o < FITH) ? o : (FITH - 1);
    const int h  = tid >> 8;          // 0 -> atoms 0,1 ; 1 -> atoms 2,3
    const int a0 = 2 * h, a1 = 2 * h + 1;
    float* hA = aux;                  // xyz staging dead
    float* hB = aux + 960;
    float* red = aux + 1920;          // [4 atoms][4 waves-per-half]
    float v0, v1;

    // ---- layer 0: K=1600, bf16 weight rows ----
    {
        const uint4* wrow = (const uint4*)(u0 + W0_U + (size_t)(t * FITH + oc) * DDIM);
        float bias = fb0[t * FITH + oc];
        v0 = bias; v1 = bias;
        const float4* d0p = (const float4*)&D4[a0][0];
        const float4* d1p = (const float4*)&D4[a1][0];
#pragma unroll 2
        for (int q = 0; q < 200; ++q) {
            uint4 wq = wrow[q];
            float w0 = __uint_as_float(wq.x << 16), w1 = __uint_as_float(wq.x & 0xFFFF0000u);
            float w2 = __uint_as_float(wq.y << 16), w3 = __uint_as_float(wq.y & 0xFFFF0000u);
            float w4 = __uint_as_float(wq.z << 16), w5 = __uint_as_float(wq.z & 0xFFFF0000u);
            float w6 = __uint_as_float(wq.w << 16), w7 = __uint_as_float(wq.w & 0xFFFF0000u);
            float4 xa = d0p[2 * q], xb = d0p[2 * q + 1];
            float4 ya = d1p[2 * q], yb = d1p[2 * q + 1];
            v0 = fmaf(xa.x, w0, v0); v0 = fmaf(xa.y, w1, v0); v0 = fmaf(xa.z, w2, v0); v0 = fmaf(xa.w, w3, v0);
            v0 = fmaf(xb.x, w4, v0); v0 = fmaf(xb.y, w5, v0); v0 = fmaf(xb.z, w6, v0); v0 = fmaf(xb.w, w7, v0);
            v1 = fmaf(ya.x, w0, v1); v1 = fmaf(ya.y, w1, v1); v1 = fmaf(ya.z, w2, v1); v1 = fmaf(ya.w, w3, v1);
            v1 = fmaf(yb.x, w4, v1); v1 = fmaf(yb.y, w5, v1); v1 = fmaf(yb.z, w6, v1); v1 = fmaf(yb.w, w7, v1);
        }
    }
    __syncthreads();   // aux (xyz) -> hA transition
    if (o < FITH) { hA[a0 * FITH + o] = ftanh(v0); hA[a1 * FITH + o] = ftanh(v1); }
    __syncthreads();

    // ---- layer 1: K=240 ----
    {
        const uint4* wrow = (const uint4*)(u0 + W1_U + (size_t)(t * FITH + oc) * FITH);
        float bias = fb1[t * FITH + oc];
        v0 = bias; v1 = bias;
        const float4* h0p = (const float4*)&hA[a0 * FITH];
        const float4* h1p = (const float4*)&hA[a1 * FITH];
#pragma unroll 2
        for (int q = 0; q < 30; ++q) {
            uint4 wq = wrow[q];
            float w0 = __uint_as_float(wq.x << 16), w1 = __uint_as_float(wq.x & 0xFFFF0000u);
            float w2 = __uint_as_float(wq.y << 16), w3 = __uint_as_float(wq.y & 0xFFFF0000u);
            float w4 = __uint_as_float(wq.z << 16), w5 = __uint_as_float(wq.z & 0xFFFF0000u);
            float w6 = __uint_as_float(wq.w << 16), w7 = __uint_as_float(wq.w & 0xFFFF0000u);
            float4 xa = h0p[2 * q], xb = h0p[2 * q + 1];
            float4 ya = h1p[2 * q], yb = h1p[2 * q + 1];
            v0 = fmaf(xa.x, w0, v0); v0 = fmaf(xa.y, w1, v0); v0 = fmaf(xa.z, w2, v0); v0 = fmaf(xa.w, w3, v0);
            v0 = fmaf(xb.x, w4, v0); v0 = fmaf(xb.y, w5, v0); v0 = fmaf(xb.z, w6, v0); v0 = fmaf(xb.w, w7, v0);
            v1 = fmaf(ya.x, w0, v1); v1 = fmaf(ya.y, w1, v1); v1 = fmaf(ya.z, w2, v1); v1 = fmaf(ya.w, w3, v1);
            v1 = fmaf(yb.x, w4, v1); v1 = fmaf(yb.y, w5, v1); v1 = fmaf(yb.z, w6, v1); v1 = fmaf(yb.w, w7, v1);
        }
    }
    if (o < FITH) {
        hB[a0 * FITH + o] = hA[a0 * FITH + o] + ftanh(v0);
        hB[a1 * FITH + o] = hA[a1 * FITH + o] + ftanh(v1);
    }
    __syncthreads();

    // ---- layer 2: K=240 (h2 overwrites hA) ----
    {
        const uint4* wrow = (const uint4*)(u0 + W2_U + (size_t)(t * FITH + oc) * FITH);
        float bias = fb2[t * FITH + oc];
        v0 = bias; v1 = bias;
        const float4* h0p = (const float4*)&hB[a0 * FITH];
        const float4* h1p = (const float4*)&hB[a1 * FITH];
#pragma unroll 2
        for (int q = 0; q < 30; ++q) {
            uint4 wq = wrow[q];
            float w0 = __uint_as_float(wq.x << 16), w1 = __uint_as_float(wq.x & 0xFFFF0000u);
            float w2 = __uint_as_float(wq.y << 16), w3 = __uint_as_float(wq.y & 0xFFFF0000u);
            float w4 = __uint_as_float(wq.z << 16), w5 = __uint_as_float(wq.z & 0xFFFF0000u);
            float w6 = __uint_as_float(wq.w << 16), w7 = __uint_as_float(wq.w & 0xFFFF0000u);
            float4 xa = h0p[2 * q], xb = h0p[2 * q + 1];
            float4 ya = h1p[2 * q], yb = h1p[2 * q + 1];
            v0 = fmaf(xa.x, w0, v0); v0 = fmaf(xa.y, w1, v0); v0 = fmaf(xa.z, w2, v0); v0 = fmaf(xa.w, w3, v0);
            v0 = fmaf(xb.x, w4, v0); v0 = fmaf(xb.y, w5, v0); v0 = fmaf(xb.z, w6, v0); v0 = fmaf(xb.w, w7, v0);
            v1 = fmaf(ya.x, w0, v1); v1 = fmaf(ya.y, w1, v1); v1 = fmaf(ya.z, w2, v1); v1 = fmaf(ya.w, w3, v1);
            v1 = fmaf(yb.x, w4, v1); v1 = fmaf(yb.y, w5, v1); v1 = fmaf(yb.z, w6, v1); v1 = fmaf(yb.w, w7, v1);
        }
    }
    __syncthreads();
    if (o < FITH) {
        hA[a0 * FITH + o] = hB[a0 * FITH + o] + ftanh(v0);
        hA[a1 * FITH + o] = hB[a1 * FITH + o] + ftanh(v1);
    }
    __syncthreads();

    // ---- final dot + Ei + Etot atomics ----
    {
        float w3 = fW3[t * FITH + oc];
        float p0 = 0.0f, p1 = 0.0f;
        if (o < FITH) { p0 = hA[a0 * FITH + o] * w3; p1 = hA[a1 * FITH + o] * w3; }
#pragma unroll
        for (int off = 32; off > 0; off >>= 1) {
            p0 += __shfl_down(p0, off, 64);
            p1 += __shfl_down(p1, off, 64);
        }
        int w = tid >> 6;          // 0..7
        if ((tid & 63) == 0) { red[a0 * 4 + (w & 3)] = p0; red[a1 * 4 + (w & 3)] = p1; }
    }
    __syncthreads();
    if (tid < 4) {
        float e = red[tid * 4 + 0] + red[tid * 4 + 1] + red[tid * 4 + 2] + red[tid * 4 + 3]
                + fb3[t] + eshift[t];
        out[4 + tid * NAT + n] = e;
        atomicAdd(&out[tid], e);
    }
}

// ================= fallback (ws too small): monolithic per-atom kernel =================
__global__ void dp_atom_kernel(
    const int* __restrict__ itype, const float* __restrict__ imagedr,
    const float* __restrict__ davg, const float* __restrict__ dstd,
    const float* __restrict__ eW0, const float* __restrict__ eb0,
    const float* __restrict__ eW1, const float* __restrict__ eb1,
    const float* __restrict__ eW2, const float* __restrict__ eb2,
    const float* __restrict__ fW0, const float* __restrict__ fb0,
    const float* __restrict__ fW1, const float* __restrict__ fb1,
    const float* __restrict__ fW2, const float* __restrict__ fb2,
    const float* __restrict__ fW3, const float* __restrict__ fb3,
    const float* __restrict__ eshift, float* __restrict__ out)
{
    __shared__ __align__(16) float4 rn4[NNEI];
    __shared__ __align__(16) float  xyz[4 * EMB];
    __shared__ __align__(16) float  h0s[100 * 25];
    __shared__ __align__(16) float  smem[100 * 52];
    const int atom = blockIdx.x;
    const int n = atom & (NAT - 1);
    const int tid = threadIdx.x;
    const int t = itype[n];
    for (int m = tid; m < NNEI; m += 256) {
        float4 dr = ((const float4*)imagedr)[(size_t)atom * NNEI + m];
        float R = dr.x;
        float S = calc_S(R);
        float Rsafe = (R > 1e-5f) ? R : 1.0f;
        float sr = (fabsf(R) > 1e-5f) ? (S / Rsafe) : 0.0f;
        float4 av = ((const float4*)davg)[t * NNEI + m];
        float4 sd = ((const float4*)dstd)[t * NNEI + m];
        float4 rv;
        rv.x = (S - av.x) / sd.x; rv.y = (sr * dr.y - av.y) / sd.y;
        rv.z = (sr * dr.z - av.z) / sd.z; rv.w = (sr * dr.w - av.w) / sd.w;
        rn4[m] = rv;
    }
    const int c = tid & 127; const int mh = tid >> 7;
    float xp0 = 0, xp1 = 0, xp2 = 0, xp3 = 0;
    for (int j = 0; j < NT; ++j) {
        const int wb = t * NT + j;
        const float* W0 = eW0 + wb * 25; const float* B0 = eb0 + wb * 25;
        const float* W1 = eW1 + wb * 1250; const float* B1 = eb1 + wb * 50;
        const float* W2 = eW2 + wb * 5000; const float* B2 = eb2 + wb * 100;
        __syncthreads();
        for (int idx = tid; idx < 2500; idx += 256) {
            int m = idx / 25, a = idx - m * 25;
            h0s[idx] = ftanh(fmaf(rn4[j * 100 + m].x, W0[a], B0[a]));
        }
        __syncthreads();
        for (int idx = tid; idx < 5000; idx += 256) {
            int m = idx / 50, cc = idx - m * 50;
            const float* h0m = h0s + m * 25;
            float acc = B1[cc];
#pragma unroll
            for (int a = 0; a < 25; ++a) acc = fmaf(h0m[a], W1[a * 50 + cc], acc);
            smem[m * 52 + cc] = ftanh(acc) + h0m[(cc < 25) ? cc : cc - 25];
        }
        for (int idx = tid; idx < 200; idx += 256)
            smem[(idx >> 1) * 52 + 50 + (idx & 1)] = 0.0f;
        __syncthreads();
        if (c < EMB) {
            float w2c[52];
#pragma unroll
            for (int a = 0; a < 50; ++a) w2c[a] = W2[a * EMB + c];
            w2c[50] = 0; w2c[51] = 0;
            const float bc = B2[c];
            const int sk = (c < 50) ? c : c - 50;
            for (int i = 0; i < 50; ++i) {
                int m = mh * 50 + i;
                const float* h1m = smem + m * 52;
                float acc = bc;
#pragma unroll
                for (int q = 0; q < 13; ++q) {
                    float4 hv = ((const float4*)h1m)[q];
                    acc = fmaf(hv.x, w2c[4 * q], acc); acc = fmaf(hv.y, w2c[4 * q + 1], acc);
                    acc = fmaf(hv.z, w2c[4 * q + 2], acc); acc = fmaf(hv.w, w2c[4 * q + 3], acc);
                }
                float g = ftanh(acc) + h1m[sk];
                float4 rm = rn4[j * 100 + m];
                xp0 = fmaf(rm.x, g, xp0); xp1 = fmaf(rm.y, g, xp1);
                xp2 = fmaf(rm.z, g, xp2); xp3 = fmaf(rm.w, g, xp3);
            }
        }
    }
    __syncthreads();
    const float inv = 1.0f / 200.0f;
    if (mh == 0 && c < EMB) {
        xyz[c] = xp0 * inv; xyz[EMB + c] = xp1 * inv;
        xyz[2 * EMB + c] = xp2 * inv; xyz[3 * EMB + c] = xp3 * inv;
    }
    __syncthreads();
    if (mh == 1 && c < EMB) {
        xyz[c] += xp0 * inv; xyz[EMB + c] += xp1 * inv;
        xyz[2 * EMB + c] += xp2 * inv; xyz[3 * EMB + c] += xp3 * inv;
    }
    __syncthreads();
    float* Dld = smem;
    for (int idx = tid; idx < DDIM; idx += 256) {
        int cc = idx >> 4, d = idx & 15;
        Dld[idx] = xyz[cc] * xyz[d] + xyz[EMB + cc] * xyz[EMB + d]
                 + xyz[2 * EMB + cc] * xyz[2 * EMB + d] + xyz[3 * EMB + cc] * xyz[3 * EMB + d];
    }
    __syncthreads();
    float* hA = smem + DDIM; float* hB = hA + FITH; float* h2 = hB + FITH; float* red = h2 + FITH;
    if (tid < FITH) {
        const float* W = fW0 + (size_t)t * DDIM * FITH;
        float acc = fb0[t * FITH + tid];
        for (int f = 0; f < DDIM; f += 4) {
            float4 dv = *(const float4*)(Dld + f);
            acc = fmaf(dv.x, W[f * FITH + tid], acc); acc = fmaf(dv.y, W[(f + 1) * FITH + tid], acc);
            acc = fmaf(dv.z, W[(f + 2) * FITH + tid], acc); acc = fmaf(dv.w, W[(f + 3) * FITH + tid], acc);
        }
        hA[tid] = ftanh(acc);
    }
    __syncthreads();
    if (tid < FITH) {
        const float* W = fW1 + t * FITH * FITH;
        float acc = fb1[t * FITH + tid];
        for (int f = 0; f < FITH; f += 4) {
            float4 hv = *(const float4*)(hA + f);
            acc = fmaf(hv.x, W[f * FITH + tid], acc); acc = fmaf(hv.y, W[(f + 1) * FITH + tid], acc);
            acc = fmaf(hv.z, W[(f + 2) * FITH + tid], acc); acc = fmaf(hv.w, W[(f + 3) * FITH + tid], acc);
        }
        hB[tid] = hA[tid] + ftanh(acc);
    }
    __syncthreads();
    if (tid < FITH) {
        const float* W = fW2 + t * FITH * FITH;
        float acc = fb2[t * FITH + tid];
        for (int f = 0; f < FITH; f += 4) {
            float4 hv = *(const float4*)(hB + f);
            acc = fmaf(hv.x, W[f * FITH + tid], acc); acc = fmaf(hv.y, W[(f + 1) * FITH + tid], acc);
            acc = fmaf(hv.z, W[(f + 2) * FITH + tid], acc); acc = fmaf(hv.w, W[(f + 3) * FITH + tid], acc);
        }
        h2[tid] = hB[tid] + ftanh(acc);
    }
    __syncthreads();
    float p = (tid < FITH) ? h2[tid] * fW3[t * FITH + tid] : 0.0f;
#pragma unroll
    for (int off = 32; off > 0; off >>= 1) p += __shfl_down(p, off, 64);
    if ((tid & 63) == 0) red[tid >> 6] = p;
    __syncthreads();
    if (tid == 0) out[4 + atom] = red[0] + red[1] + red[2] + red[3] + fb3[t] + eshift[t];
}

__global__ void etot_kernel(float* __restrict__ out) {
    const int b = blockIdx.x;
    float s = 0.0f;
    for (int n = threadIdx.x; n < NAT; n += 256) s += out[4 + b * NAT + n];
#pragma unroll
    for (int off = 32; off > 0; off >>= 1) s += __shfl_down(s, off, 64);
    __shared__ float rr[4];
    if ((threadIdx.x & 63) == 0) rr[threadIdx.x >> 6] = s;
    __syncthreads();
    if (threadIdx.x == 0) out[b] = rr[0] + rr[1] + rr[2] + rr[3];
}

extern "C" void kernel_launch(void* const* d_in, const int* in_sizes, int n_in,
                              void* d_out, int out_size, void* d_ws, size_t ws_size,
                              hipStream_t stream) {
    const int*   itype   = (const int*)  d_in[1];
    const float* imagedr = (const float*)d_in[3];
    const float* davg    = (const float*)d_in[5];
    const float* dstd    = (const float*)d_in[6];
    const float* eW0     = (const float*)d_in[7];
    const float* eb0     = (const float*)d_in[8];
    const float* eW1     = (const float*)d_in[9];
    const float* eb1     = (const float*)d_in[10];
    const float* eW2     = (const float*)d_in[11];
    const float* eb2     = (const float*)d_in[12];
    const float* fW0     = (const float*)d_in[13];
    const float* fb0     = (const float*)d_in[14];
    const float* fW1     = (const float*)d_in[15];
    const float* fb1     = (const float*)d_in[16];
    const float* fW2     = (const float*)d_in[17];
    const float* fb2     = (const float*)d_in[18];
    const float* fW3     = (const float*)d_in[19];
    const float* fb3     = (const float*)d_in[20];
    const float* eshift  = (const float*)d_in[21];
    float* out = (float*)d_out;
    float* ws  = (float*)d_ws;

    if (ws_size >= WS_NEED) {
        wtrans_kernel<<<3900, 256, 0, stream>>>(fW0, fW1, fW2, ws, out);
        table_kernel<<<1024, 256, 0, stream>>>(davg, dstd, eW0, eb0, eW1, eb1, eW2, eb2, ws);
        embed_kernel<<<NATOMS, 128, 0, stream>>>(itype, imagedr, davg, dstd, ws, ws + XYZ_F);
        fit_kernel<<<NAT, 512, 0, stream>>>(itype, ws, fb0, fb1, fb2, fW3, fb3, eshift, out);
    } else {
        dp_atom_kernel<<<NATOMS, 256, 0, stream>>>(itype, imagedr, davg, dstd,
            eW0, eb0, eW1, eb1, eW2, eb2,
            fW0, fb0, fW1, fb1, fW2, fb2, fW3, fb3, eshift, out);
        etot_kernel<<<BSZ, 256, 0, stream>>>(out);
    }
}

// Round 5
// 194.729 us; speedup vs baseline: 2.0048x; 1.4277x over previous
//
#include <hip/hip_runtime.h>
#include <math.h>

#define NT 2
#define BSZ 4
#define NAT 512
#define NATOMS 2048
#define NNEI 200
#define EMB 100
#define FITH 240
#define DDIM 1600
#define TBK 1024

// ---- ws layout ----
// float region: [0..8) ranges (smin,scal per net), [16..1552) concat biases (3x512)
// ushort region at byte USH_BYTE:
#define USH_BYTE 6208
#define TBL_U   0                          // 4*1024*100 = 409600
#define W0T_U   409600                     // [512][1600] = 819200
#define W1T_U   (W0T_U + 819200)           // [512][512]  = 262144
#define W2T_U   (W1T_U + 262144)           // 262144
#define D_U     (W2T_U + 262144)           // [2048][1600] = 3276800 (H1 aliases here later)
#define H0_U    (D_U + 3276800)            // [2048][512] = 1048576
#define USH_END (H0_U + 1048576)           // 6078464
#define WS_NEED ((size_t)USH_BYTE + (size_t)USH_END * 2)   // ~12.16 MB

typedef short s8v __attribute__((ext_vector_type(8)));
typedef float f16v __attribute__((ext_vector_type(16)));

__device__ __forceinline__ float ftanh(float x) {
    float ax = fabsf(x);
    float e = __expf(2.0f * ax);
    float t = 1.0f - __fdividef(2.0f, e + 1.0f);
    return (x < 0.0f) ? -t : t;
}
__device__ __forceinline__ unsigned short f2bf(float f) {
    unsigned u = __float_as_uint(f);
    u += 0x7FFFu + ((u >> 16) & 1u);
    return (unsigned short)(u >> 16);
}
__device__ __forceinline__ float bf2f(unsigned short s) {
    return __uint_as_float(((unsigned)s) << 16);
}
__device__ __forceinline__ float calc_S(float R) {
    float Rsafe = (R > 1e-5f) ? R : 1.0f;
    float u = (R - 0.5f) * (1.0f / 5.5f);
    float uu = u * u;
    float mid = (u * uu * (-6.0f * uu + 15.0f * u - 10.0f) + 1.0f) / Rsafe;
    float S = 0.0f;
    if (R > 0.0f && R < 0.5f)      S = 1.0f / Rsafe;
    else if (R > 0.5f && R < 6.0f) S = mid;
    return S;
}

// ---------- K1: build concat/padded bf16 weight layouts + biases; zero Etot ----------
// W0T[n][k] (n<512,k<1600), W1T/W2T[n][k] (512x512 block-diag, segments at 0 and 256)
#define N_W0 819200
#define N_W1 262144
#define N_W2 262144
#define N_B  1536
__global__ void wtrans_kernel(const float* __restrict__ fW0, const float* __restrict__ fW1,
                              const float* __restrict__ fW2,
                              const float* __restrict__ fb0, const float* __restrict__ fb1,
                              const float* __restrict__ fb2,
                              float* __restrict__ ws, float* __restrict__ out) {
    if (blockIdx.x == 0 && threadIdx.x < 4) out[threadIdx.x] = 0.0f;
    unsigned short* u0 = (unsigned short*)((char*)ws + USH_BYTE);
    int id = blockIdx.x * 256 + threadIdx.x;
    if (id < N_W0) {
        int k = id / 512, n = id - k * 512;
        float v = 0.0f;
        if (n < 240)                 v = fW0[(size_t)k * 240 + n];
        else if (n >= 256 && n < 496) v = fW0[(size_t)(1600 + k) * 240 + (n - 256)];
        u0[W0T_U + (size_t)n * 1600 + k] = f2bf(v);
        return;
    }
    id -= N_W0;
    if (id < N_W1) {
        int k = id / 512, n = id - k * 512;
        float v = 0.0f;
        if (n < 240 && k < 240)      v = fW1[(size_t)k * 240 + n];
        else if (n >= 256 && n < 496 && k >= 256 && k < 496)
                                     v = fW1[(size_t)(240 + (k - 256)) * 240 + (n - 256)];
        u0[W1T_U + (size_t)n * 512 + k] = f2bf(v);
        return;
    }
    id -= N_W1;
    if (id < N_W2) {
        int k = id / 512, n = id - k * 512;
        float v = 0.0f;
        if (n < 240 && k < 240)      v = fW2[(size_t)k * 240 + n];
        else if (n >= 256 && n < 496 && k >= 256 && k < 496)
                                     v = fW2[(size_t)(240 + (k - 256)) * 240 + (n - 256)];
        u0[W2T_U + (size_t)n * 512 + k] = f2bf(v);
        return;
    }
    id -= N_W2;
    if (id < N_B) {
        int l = id / 512, n = id - l * 512;
        const float* fb = (l == 0) ? fb0 : (l == 1) ? fb1 : fb2;
        float v = 0.0f;
        if (n < 240)                 v = fb[n];
        else if (n >= 256 && n < 496) v = fb[240 + (n - 256)];
        ws[16 + l * 512 + n] = v;
    }
}

// ---------- K2: embedding-net table build (covering range from davg/dstd) ----------
__global__ void __launch_bounds__(256) table_kernel(
    const float* __restrict__ davg, const float* __restrict__ dstd,
    const float* __restrict__ eW0, const float* __restrict__ eb0,
    const float* __restrict__ eW1, const float* __restrict__ eb1,
    const float* __restrict__ eW2, const float* __restrict__ eb2,
    float* __restrict__ ws)
{
    __shared__ float los[100], his[100];
    __shared__ float rng[2];
    __shared__ float h0s[8][25];
    __shared__ float h1s[8][50];
    const int bx = blockIdx.x;               // 512 blocks: nid (4) x 128
    const int nid = bx >> 7;
    const int kb  = (bx & 127) * 8;
    const int t = nid >> 1, j = nid & 1;
    const int tid = threadIdx.x;

    if (tid < 100) {
        int m = j * 100 + tid;
        float av = davg[(t * NNEI + m) * 4];
        float sd = dstd[(t * NNEI + m) * 4];
        float inv = __fdividef(1.0f, sd);
        float a = (0.0f - av) * inv;         // S in [0,2] for this data
        float b = (2.0f - av) * inv;
        los[tid] = fminf(a, b);
        his[tid] = fmaxf(a, b);
    }
    __syncthreads();
    if (tid == 0) {
        float lo = los[0], hi = his[0];
        for (int i = 1; i < 100; ++i) { lo = fminf(lo, los[i]); hi = fmaxf(hi, his[i]); }
        rng[0] = lo; rng[1] = hi - lo;
        if (kb == 0) {
            ws[nid * 2] = lo;
            ws[nid * 2 + 1] = (float)(TBK - 1) / (hi - lo);
        }
    }
    __syncthreads();
    const float smin = rng[0], span = rng[1];
    const float* W0 = eW0 + nid * 25;
    const float* B0 = eb0 + nid * 25;
    if (tid < 200) {
        int q = tid / 25, a = tid % 25;
        float s = smin + span * ((float)(kb + q) * (1.0f / (TBK - 1)));
        h0s[q][a] = ftanh(fmaf(s, W0[a], B0[a]));
    }
    __syncthreads();
    const float* W1 = eW1 + nid * 1250;
    const float* B1 = eb1 + nid * 50;
    for (int idx = tid; idx < 400; idx += 256) {
        int q = idx / 50, cc = idx % 50;
        float acc = B1[cc];
#pragma unroll
        for (int a = 0; a < 25; ++a) acc = fmaf(h0s[q][a], W1[a * 50 + cc], acc);
        h1s[q][cc] = ftanh(acc) + h0s[q][(cc < 25) ? cc : cc - 25];
    }
    __syncthreads();
    const float* W2 = eW2 + nid * 5000;
    const float* B2 = eb2 + nid * 100;
    unsigned short* tblu = (unsigned short*)((char*)ws + USH_BYTE) + TBL_U;
    for (int idx = tid; idx < 800; idx += 256) {
        int q = idx / 100, c = idx % 100;
        float acc = B2[c];
#pragma unroll
        for (int a = 0; a < 50; ++a) acc = fmaf(h1s[q][a], W2[a * 100 + c], acc);
        float g = ftanh(acc) + h1s[q][(c < 50) ? c : c - 50];
        tblu[(size_t)(nid * TBK + kb + q) * 100 + c] = f2bf(g);
    }
}

// ---------- K3: embed (table interp) -> writes D bf16 [2048][1600] ----------
__global__ void __launch_bounds__(128) embed_kernel(
    const int* __restrict__ itype, const float* __restrict__ imagedr,
    const float* __restrict__ davg, const float* __restrict__ dstd,
    float* __restrict__ ws)
{
    __shared__ __align__(16) float4 srn[NNEI];
    __shared__ float sx[NNEI];
    __shared__ float part[2][400];
    const int atom = blockIdx.x;
    const int n = atom & (NAT - 1);
    const int tid = threadIdx.x;
    const int t = itype[n];
    unsigned short* u0 = (unsigned short*)((char*)ws + USH_BYTE);

    const float sm0 = ws[(t * 2 + 0) * 2], sc0 = ws[(t * 2 + 0) * 2 + 1];
    const float sm1 = ws[(t * 2 + 1) * 2], sc1 = ws[(t * 2 + 1) * 2 + 1];

    for (int m = tid; m < NNEI; m += 128) {
        float4 dr = ((const float4*)imagedr)[(size_t)atom * NNEI + m];
        float R = dr.x;
        float S = calc_S(R);
        float Rsafe = (R > 1e-5f) ? R : 1.0f;
        float sr = (fabsf(R) > 1e-5f) ? (S / Rsafe) : 0.0f;
        float4 av = ((const float4*)davg)[t * NNEI + m];
        float4 sd = ((const float4*)dstd)[t * NNEI + m];
        float4 rv;
        rv.x = (S         - av.x) / sd.x;
        rv.y = (sr * dr.y - av.y) / sd.y;
        rv.z = (sr * dr.z - av.z) / sd.z;
        rv.w = (sr * dr.w - av.w) / sd.w;
        srn[m] = rv;
        float smin = (m >= 100) ? sm1 : sm0;
        float scal = (m >= 100) ? sc1 : sc0;
        sx[m] = fminf(fmaxf((rv.x - smin) * scal, 0.0f), (float)(TBK - 2) + 0.9999f);
    }
    __syncthreads();

    const int w = tid >> 6, lane = tid & 63;
    const unsigned short* T = u0 + TBL_U + (size_t)(t * 2 + w) * TBK * EMB;
    const bool hi = (lane < 36);
    float xA0 = 0, xA1 = 0, xA2 = 0, xA3 = 0;
    float xB0 = 0, xB1 = 0, xB2 = 0, xB3 = 0;
    for (int mi = 0; mi < 100; ++mi) {
        int m = w * 100 + mi;
        float4 rv = srn[m];
        float x = sx[m];
        int i = (int)x;
        float f = x - (float)i;
        const unsigned short* Tr = T + (size_t)i * EMB;
        float g0 = bf2f(Tr[lane]);
        float g1 = bf2f(Tr[EMB + lane]);
        float g = fmaf(f, g1 - g0, g0);
        xA0 = fmaf(rv.x, g, xA0); xA1 = fmaf(rv.y, g, xA1);
        xA2 = fmaf(rv.z, g, xA2); xA3 = fmaf(rv.w, g, xA3);
        if (hi) {
            float h0v = bf2f(Tr[64 + lane]);
            float h1v = bf2f(Tr[EMB + 64 + lane]);
            float g2 = fmaf(f, h1v - h0v, h0v);
            xB0 = fmaf(rv.x, g2, xB0); xB1 = fmaf(rv.y, g2, xB1);
            xB2 = fmaf(rv.z, g2, xB2); xB3 = fmaf(rv.w, g2, xB3);
        }
    }
    part[w][0 * 100 + lane] = xA0; part[w][1 * 100 + lane] = xA1;
    part[w][2 * 100 + lane] = xA2; part[w][3 * 100 + lane] = xA3;
    if (hi) {
        part[w][0 * 100 + 64 + lane] = xB0; part[w][1 * 100 + 64 + lane] = xB1;
        part[w][2 * 100 + 64 + lane] = xB2; part[w][3 * 100 + 64 + lane] = xB3;
    }
    __syncthreads();
    const float inv = 1.0f / 200.0f;
    for (int idx = tid; idx < 400; idx += 128)
        part[0][idx] = (part[0][idx] + part[1][idx]) * inv;   // xyz[4][100]
    __syncthreads();
    unsigned short* Drow = u0 + D_U + (size_t)atom * DDIM;
    const float* xt = part[0];
    for (int idx = tid; idx < DDIM; idx += 128) {
        int c = idx >> 4, d = idx & 15;
        float s = xt[c] * xt[d] + xt[100 + c] * xt[100 + d]
                + xt[200 + c] * xt[200 + d] + xt[300 + c] * xt[300 + d];
        Drow[idx] = f2bf(s);
    }
}

// ---------- K4: MFMA GEMM: Out[2048][512] = epi(A[2048][K] x BT^T + bias) ----------
// BT is [512 rows n][ldb cols k]. diag: n-tiles >=4 use k in [256,512).
__global__ void __launch_bounds__(256) gemm_kernel(
    const unsigned short* __restrict__ A, int lda,
    const unsigned short* __restrict__ BT, int ldb,
    const float* __restrict__ bias,
    const unsigned short* __restrict__ Res,
    unsigned short* __restrict__ Out, int ldo,
    int ksteps, int diag)
{
    __shared__ unsigned short Al[64][40];
    __shared__ unsigned short Bl[64][40];
    const int nt = blockIdx.x;      // 0..7
    const int mt = blockIdx.y;      // 0..31
    const int tid = threadIdx.x;
    const int w = tid >> 6, lane = tid & 63;
    const int wm = (w >> 1) * 32, wn = (w & 1) * 32;
    const int m0 = mt * 64, n0 = nt * 64;
    const int k_start = (diag && nt >= 4) ? 256 : 0;
    const int r4 = tid >> 2, c8 = (tid & 3) * 8;

    f16v acc;
#pragma unroll
    for (int i = 0; i < 16; ++i) acc[i] = 0.0f;

    for (int kt = 0; kt < ksteps; ++kt) {
        const int kc = k_start + kt * 32 + c8;
        uint4 av = *(const uint4*)(A  + (size_t)(m0 + r4) * lda + kc);
        uint4 bv = *(const uint4*)(BT + (size_t)(n0 + r4) * ldb + kc);
        __syncthreads();
        *(uint4*)&Al[r4][c8] = av;
        *(uint4*)&Bl[r4][c8] = bv;
        __syncthreads();
        const int fr = (lane >> 5) * 8;
        s8v a0 = *(const s8v*)&Al[wm + (lane & 31)][fr];
        s8v b0 = *(const s8v*)&Bl[wn + (lane & 31)][fr];
        acc = __builtin_amdgcn_mfma_f32_32x32x16_bf16(a0, b0, acc, 0, 0, 0);
        s8v a1 = *(const s8v*)&Al[wm + (lane & 31)][16 + fr];
        s8v b1 = *(const s8v*)&Bl[wn + (lane & 31)][16 + fr];
        acc = __builtin_amdgcn_mfma_f32_32x32x16_bf16(a1, b1, acc, 0, 0, 0);
    }

    const int gcol = n0 + wn + (lane & 31);
    const float bv = bias[gcol];
#pragma unroll
    for (int r = 0; r < 16; ++r) {
        int row = (r & 3) + 8 * (r >> 2) + 4 * (lane >> 5);
        size_t gi = (size_t)(m0 + wm + row) * ldo + gcol;
        float v = ftanh(acc[r] + bv);
        if (Res) v += bf2f(Res[gi]);
        Out[gi] = f2bf(v);
    }
}

// ---------- K5: final dot + Ei + Etot ----------
__global__ void __launch_bounds__(256) final_kernel(
    const int* __restrict__ itype, const float* ws,
    const float* __restrict__ fW3, const float* __restrict__ fb3,
    const float* __restrict__ eshift, float* __restrict__ out)
{
    __shared__ float sred[4];
    const int tid = threadIdx.x;
    const int w = tid >> 6, lane = tid & 63;
    const int atom = blockIdx.x * 4 + w;          // 0..2047
    const int n = atom & (NAT - 1);
    const int t = itype[n];
    const unsigned short* H = (const unsigned short*)((const char*)ws + USH_BYTE) + H0_U;
    const unsigned short* Hrow = H + (size_t)atom * 512 + t * 256;
    float p = 0.0f;
    if (lane < 60) {
        ushort4 hv = *(const ushort4*)(Hrow + lane * 4);
        const float* w3p = fW3 + t * 240 + lane * 4;
        p = bf2f(hv.x) * w3p[0] + bf2f(hv.y) * w3p[1]
          + bf2f(hv.z) * w3p[2] + bf2f(hv.w) * w3p[3];
    }
#pragma unroll
    for (int off = 32; off > 0; off >>= 1) p += __shfl_down(p, off, 64);
    if (lane == 0) {
        float e = p + fb3[t] + eshift[t];
        out[4 + atom] = e;
        sred[w] = e;
    }
    __syncthreads();
    if (tid == 0) {
        int b = (blockIdx.x * 4) >> 9;
        atomicAdd(&out[b], sred[0] + sred[1] + sred[2] + sred[3]);
    }
}

// ================= fallback (small ws): monolithic per-atom =================
__global__ void dp_atom_kernel(
    const int* __restrict__ itype, const float* __restrict__ imagedr,
    const float* __restrict__ davg, const float* __restrict__ dstd,
    const float* __restrict__ eW0, const float* __restrict__ eb0,
    const float* __restrict__ eW1, const float* __restrict__ eb1,
    const float* __restrict__ eW2, const float* __restrict__ eb2,
    const float* __restrict__ fW0, const float* __restrict__ fb0,
    const float* __restrict__ fW1, const float* __restrict__ fb1,
    const float* __restrict__ fW2, const float* __restrict__ fb2,
    const float* __restrict__ fW3, const float* __restrict__ fb3,
    const float* __restrict__ eshift, float* __restrict__ out)
{
    __shared__ __align__(16) float4 rn4[NNEI];
    __shared__ __align__(16) float  xyz[4 * EMB];
    __shared__ __align__(16) float  h0s[100 * 25];
    __shared__ __align__(16) float  smem[100 * 52];
    const int atom = blockIdx.x;
    const int n = atom & (NAT - 1);
    const int tid = threadIdx.x;
    const int t = itype[n];
    for (int m = tid; m < NNEI; m += 256) {
        float4 dr = ((const float4*)imagedr)[(size_t)atom * NNEI + m];
        float R = dr.x;
        float S = calc_S(R);
        float Rsafe = (R > 1e-5f) ? R : 1.0f;
        float sr = (fabsf(R) > 1e-5f) ? (S / Rsafe) : 0.0f;
        float4 av = ((const float4*)davg)[t * NNEI + m];
        float4 sd = ((const float4*)dstd)[t * NNEI + m];
        float4 rv;
        rv.x = (S - av.x) / sd.x; rv.y = (sr * dr.y - av.y) / sd.y;
        rv.z = (sr * dr.z - av.z) / sd.z; rv.w = (sr * dr.w - av.w) / sd.w;
        rn4[m] = rv;
    }
    const int c = tid & 127; const int mh = tid >> 7;
    float xp0 = 0, xp1 = 0, xp2 = 0, xp3 = 0;
    for (int j = 0; j < NT; ++j) {
        const int wb = t * NT + j;
        const float* W0 = eW0 + wb * 25; const float* B0 = eb0 + wb * 25;
        const float* W1 = eW1 + wb * 1250; const float* B1 = eb1 + wb * 50;
        const float* W2 = eW2 + wb * 5000; const float* B2 = eb2 + wb * 100;
        __syncthreads();
        for (int idx = tid; idx < 2500; idx += 256) {
            int m = idx / 25, a = idx - m * 25;
            h0s[idx] = ftanh(fmaf(rn4[j * 100 + m].x, W0[a], B0[a]));
        }
        __syncthreads();
        for (int idx = tid; idx < 5000; idx += 256) {
            int m = idx / 50, cc = idx - m * 50;
            const float* h0m = h0s + m * 25;
            float acc = B1[cc];
#pragma unroll
            for (int a = 0; a < 25; ++a) acc = fmaf(h0m[a], W1[a * 50 + cc], acc);
            smem[m * 52 + cc] = ftanh(acc) + h0m[(cc < 25) ? cc : cc - 25];
        }
        for (int idx = tid; idx < 200; idx += 256)
            smem[(idx >> 1) * 52 + 50 + (idx & 1)] = 0.0f;
        __syncthreads();
        if (c < EMB) {
            float w2c[52];
#pragma unroll
            for (int a = 0; a < 50; ++a) w2c[a] = W2[a * EMB + c];
            w2c[50] = 0; w2c[51] = 0;
            const float bc = B2[c];
            const int sk = (c < 50) ? c : c - 50;
            for (int i = 0; i < 50; ++i) {
                int m = mh * 50 + i;
                const float* h1m = smem + m * 52;
                float acc = bc;
#pragma unroll
                for (int q = 0; q < 13; ++q) {
                    float4 hv = ((const float4*)h1m)[q];
                    acc = fmaf(hv.x, w2c[4 * q], acc); acc = fmaf(hv.y, w2c[4 * q + 1], acc);
                    acc = fmaf(hv.z, w2c[4 * q + 2], acc); acc = fmaf(hv.w, w2c[4 * q + 3], acc);
                }
                float g = ftanh(acc) + h1m[sk];
                float4 rm = rn4[j * 100 + m];
                xp0 = fmaf(rm.x, g, xp0); xp1 = fmaf(rm.y, g, xp1);
                xp2 = fmaf(rm.z, g, xp2); xp3 = fmaf(rm.w, g, xp3);
            }
        }
    }
    __syncthreads();
    const float inv = 1.0f / 200.0f;
    if (mh == 0 && c < EMB) {
        xyz[c] = xp0 * inv; xyz[EMB + c] = xp1 * inv;
        xyz[2 * EMB + c] = xp2 * inv; xyz[3 * EMB + c] = xp3 * inv;
    }
    __syncthreads();
    if (mh == 1 && c < EMB) {
        xyz[c] += xp0 * inv; xyz[EMB + c] += xp1 * inv;
        xyz[2 * EMB + c] += xp2 * inv; xyz[3 * EMB + c] += xp3 * inv;
    }
    __syncthreads();
    float* Dld = smem;
    for (int idx = tid; idx < DDIM; idx += 256) {
        int cc = idx >> 4, d = idx & 15;
        Dld[idx] = xyz[cc] * xyz[d] + xyz[EMB + cc] * xyz[EMB + d]
                 + xyz[2 * EMB + cc] * xyz[2 * EMB + d] + xyz[3 * EMB + cc] * xyz[3 * EMB + d];
    }
    __syncthreads();
    float* hA = smem + DDIM; float* hB = hA + FITH; float* h2 = hB + FITH; float* red = h2 + FITH;
    if (tid < FITH) {
        const float* W = fW0 + (size_t)t * DDIM * FITH;
        float acc = fb0[t * FITH + tid];
        for (int f = 0; f < DDIM; f += 4) {
            float4 dv = *(const float4*)(Dld + f);
            acc = fmaf(dv.x, W[f * FITH + tid], acc); acc = fmaf(dv.y, W[(f + 1) * FITH + tid], acc);
            acc = fmaf(dv.z, W[(f + 2) * FITH + tid], acc); acc = fmaf(dv.w, W[(f + 3) * FITH + tid], acc);
        }
        hA[tid] = ftanh(acc);
    }
    __syncthreads();
    if (tid < FITH) {
        const float* W = fW1 + t * FITH * FITH;
        float acc = fb1[t * FITH + tid];
        for (int f = 0; f < FITH; f += 4) {
            float4 hv = *(const float4*)(hA + f);
            acc = fmaf(hv.x, W[f * FITH + tid], acc); acc = fmaf(hv.y, W[(f + 1) * FITH + tid], acc);
            acc = fmaf(hv.z, W[(f + 2) * FITH + tid], acc); acc = fmaf(hv.w, W[(f + 3) * FITH + tid], acc);
        }
        hB[tid] = hA[tid] + ftanh(acc);
    }
    __syncthreads();
    if (tid < FITH) {
        const float* W = fW2 + t * FITH * FITH;
        float acc = fb2[t * FITH + tid];
        for (int f = 0; f < FITH; f += 4) {
            float4 hv = *(const float4*)(hB + f);
            acc = fmaf(hv.x, W[f * FITH + tid], acc); acc = fmaf(hv.y, W[(f + 1) * FITH + tid], acc);
            acc = fmaf(hv.z, W[(f + 2) * FITH + tid], acc); acc = fmaf(hv.w, W[(f + 3) * FITH + tid], acc);
        }
        h2[tid] = hB[tid] + ftanh(acc);
    }
    __syncthreads();
    float p = (tid < FITH) ? h2[tid] * fW3[t * FITH + tid] : 0.0f;
#pragma unroll
    for (int off = 32; off > 0; off >>= 1) p += __shfl_down(p, off, 64);
    if ((tid & 63) == 0) red[tid >> 6] = p;
    __syncthreads();
    if (tid == 0) out[4 + atom] = red[0] + red[1] + red[2] + red[3] + fb3[t] + eshift[t];
}

__global__ void etot_kernel(float* __restrict__ out) {
    const int b = blockIdx.x;
    float s = 0.0f;
    for (int n = threadIdx.x; n < NAT; n += 256) s += out[4 + b * NAT + n];
#pragma unroll
    for (int off = 32; off > 0; off >>= 1) s += __shfl_down(s, off, 64);
    __shared__ float rr[4];
    if ((threadIdx.x & 63) == 0) rr[threadIdx.x >> 6] = s;
    __syncthreads();
    if (threadIdx.x == 0) out[b] = rr[0] + rr[1] + rr[2] + rr[3];
}

extern "C" void kernel_launch(void* const* d_in, const int* in_sizes, int n_in,
                              void* d_out, int out_size, void* d_ws, size_t ws_size,
                              hipStream_t stream) {
    const int*   itype   = (const int*)  d_in[1];
    const float* imagedr = (const float*)d_in[3];
    const float* davg    = (const float*)d_in[5];
    const float* dstd    = (const float*)d_in[6];
    const float* eW0     = (const float*)d_in[7];
    const float* eb0     = (const float*)d_in[8];
    const float* eW1     = (const float*)d_in[9];
    const float* eb1     = (const float*)d_in[10];
    const float* eW2     = (const float*)d_in[11];
    const float* eb2     = (const float*)d_in[12];
    const float* fW0     = (const float*)d_in[13];
    const float* fb0     = (const float*)d_in[14];
    const float* fW1     = (const float*)d_in[15];
    const float* fb1     = (const float*)d_in[16];
    const float* fW2     = (const float*)d_in[17];
    const float* fb2     = (const float*)d_in[18];
    const float* fW3     = (const float*)d_in[19];
    const float* fb3     = (const float*)d_in[20];
    const float* eshift  = (const float*)d_in[21];
    float* out = (float*)d_out;
    float* ws  = (float*)d_ws;

    if (ws_size >= WS_NEED) {
        unsigned short* u0 = (unsigned short*)((char*)ws + USH_BYTE);
        const int n_wt = (N_W0 + N_W1 + N_W2 + N_B + 255) / 256;
        wtrans_kernel<<<n_wt, 256, 0, stream>>>(fW0, fW1, fW2, fb0, fb1, fb2, ws, out);
        table_kernel<<<512, 256, 0, stream>>>(davg, dstd, eW0, eb0, eW1, eb1, eW2, eb2, ws);
        embed_kernel<<<NATOMS, 128, 0, stream>>>(itype, imagedr, davg, dstd, ws);
        // layer 0: H0 = tanh(D x W0 + b0)
        gemm_kernel<<<dim3(8, 32), 256, 0, stream>>>(
            u0 + D_U, DDIM, u0 + W0T_U, DDIM, ws + 16, nullptr, u0 + H0_U, 512, 50, 0);
        // layer 1: H1 = H0 + tanh(H0 x W1 + b1)   (H1 aliases D region, D dead)
        gemm_kernel<<<dim3(8, 32), 256, 0, stream>>>(
            u0 + H0_U, 512, u0 + W1T_U, 512, ws + 16 + 512, u0 + H0_U, u0 + D_U, 512, 8, 1);
        // layer 2: H2 = H1 + tanh(H1 x W2 + b2)  -> back into H0 region
        gemm_kernel<<<dim3(8, 32), 256, 0, stream>>>(
            u0 + D_U, 512, u0 + W2T_U, 512, ws + 16 + 1024, u0 + D_U, u0 + H0_U, 512, 8, 1);
        final_kernel<<<512, 256, 0, stream>>>(itype, ws, fW3, fb3, eshift, out);
    } else {
        dp_atom_kernel<<<NATOMS, 256, 0, stream>>>(itype, imagedr, davg, dstd,
            eW0, eb0, eW1, eb1, eW2, eb2,
            fW0, fb0, fW1, fb1, fW2, fb2, fW3, fb3, eshift, out);
        etot_kernel<<<BSZ, 256, 0, stream>>>(out);
    }
}